// Round 1
// baseline (249.298 us; speedup 1.0000x reference)
//
#include <hip/hip_runtime.h>

// Problem constants (from reference)
#define NB     32      // B
#define NPTS   2048    // N
#define KNN    16      // K
#define FIN    32      // F_IN
#define FOUT   64      // F_OUT

typedef __attribute__((ext_vector_type(8))) short bf16x8;
typedef __attribute__((ext_vector_type(4))) float f32x4;

// RNE float->bf16 pack
__device__ inline unsigned bf16pk(float lo, float hi) {
    unsigned a = __float_as_uint(lo), b = __float_as_uint(hi);
    a = (a + 0x7fffu + ((a >> 16) & 1u)) >> 16;
    b = (b + 0x7fffu + ((b >> 16) & 1u)) >> 16;
    return (a & 0xffffu) | (b << 16);
}

// ---------------------------------------------------------------------------
// R-next: 3-dispatch occupancy restructure.
//   K1 sq_kernel : P4[b*N+j] = (x,y,z,sq) into ws+4MB (exact __f*_rn chain).
//   K2 knn_kernel: 1024 blocks x 512 thr, CH=8 chunks of 256. Candidates are
//                  wave-uniform float4 loads from L2 (no LDS P). LDS = 34.8 KB
//                  -> 4 blocks/CU = 32 waves/CU = 100% occupancy; grid fills
//                  the device in exactly one round (1024 = 4 * 256 CU).
//                  __launch_bounds__(512,8) caps VGPR at 64.
//   K3 mlp_kernel: previous phase B verbatim, own dispatch (regs unconstrained).
// Selection / tie-break arithmetic copied verbatim -> bit-exact kNN preserved.
// ---------------------------------------------------------------------------

#define CEA(x, y) { float _t = fminf(x, y); y = fmaxf(x, y); x = _t; }
#define CED(x, y) { float _t = fmaxf(x, y); y = fminf(x, y); x = _t; }

#define BMERGE16(dk) \
    CEA(dk[0],dk[8])  CEA(dk[1],dk[9])  CEA(dk[2],dk[10]) CEA(dk[3],dk[11]) \
    CEA(dk[4],dk[12]) CEA(dk[5],dk[13]) CEA(dk[6],dk[14]) CEA(dk[7],dk[15]) \
    CEA(dk[0],dk[4])  CEA(dk[1],dk[5])  CEA(dk[2],dk[6])  CEA(dk[3],dk[7])  \
    CEA(dk[8],dk[12]) CEA(dk[9],dk[13]) CEA(dk[10],dk[14]) CEA(dk[11],dk[15]) \
    CEA(dk[0],dk[2])  CEA(dk[1],dk[3])  CEA(dk[4],dk[6])  CEA(dk[5],dk[7])  \
    CEA(dk[8],dk[10]) CEA(dk[9],dk[11]) CEA(dk[12],dk[14]) CEA(dk[13],dk[15]) \
    CEA(dk[0],dk[1])  CEA(dk[2],dk[3])  CEA(dk[4],dk[5])  CEA(dk[6],dk[7])  \
    CEA(dk[8],dk[9])  CEA(dk[10],dk[11]) CEA(dk[12],dk[13]) CEA(dk[14],dk[15])

// ========================== K1: sq precompute ==============================
__global__ __launch_bounds__(256) void sq_kernel(
    const float* __restrict__ pos, float4* __restrict__ P4)
{
    const int i = blockIdx.x * 256 + threadIdx.x;   // 0 .. 65535
    const float px = pos[i*3 + 0];
    const float py = pos[i*3 + 1];
    const float pz = pos[i*3 + 2];
    const float sq = __fadd_rn(__fadd_rn(__fmul_rn(px,px), __fmul_rn(py,py)),
                               __fmul_rn(pz,pz));
    P4[i] = make_float4(px, py, pz, sq);
}

// ========================== K2: exact 16-NN ================================
#define CH   8
#define CHL  (NPTS / CH)    // 256

__global__ __launch_bounds__(512, 8) void knn_kernel(
    const float4* __restrict__ P4, int* __restrict__ idxws)
{
    __shared__ float V[CH * KNN * 64];   // 32 KB; reused as int JL
    __shared__ int   CNTS[CH * 64];      // 2 KB

    const int b    = blockIdx.x >> 5;    // 32 blocks per batch
    const int slab = blockIdx.x & 31;    // 64-query slab within batch
    const int t    = threadIdx.x;
    const int w    = __builtin_amdgcn_readfirstlane(t >> 6);  // chunk id, SGPR
    const int l    = t & 63;

    const float4* __restrict__ pb4 = P4 + (size_t)b * NPTS;

    const int    q  = slab * 64 + l;     // query within batch (0..2047)
    const float4 me = pb4[q];

    float dk[KNN];
    #pragma unroll
    for (int s = 0; s < KNN; ++s) dk[s] = 1e30f;

    const int j0 = w * CHL;
    for (int jb = 0; jb < CHL; jb += 8) {
        float a[8];
        #pragma unroll
        for (int i = 0; i < 8; ++i) {
            const int j = j0 + jb + i;          // wave-uniform candidate
            const float4 c = pb4[j];            // uniform L2 broadcast load
            float dot = __fadd_rn(__fadd_rn(__fmul_rn(me.x,c.x),
                                            __fmul_rn(me.y,c.y)),
                                  __fmul_rn(me.z,c.z));
            float d2 = __fsub_rn(__fadd_rn(me.w, c.w), __fmul_rn(2.0f, dot));
            a[i] = (j == q) ? 1e30f : d2;
        }
        CED(a[0],a[1]) CED(a[2],a[3]) CED(a[4],a[5]) CED(a[6],a[7])
        CED(a[0],a[2]) CED(a[1],a[3]) CED(a[4],a[6]) CED(a[5],a[7])
        CED(a[1],a[2]) CED(a[5],a[6])
        CED(a[0],a[4]) CED(a[1],a[5]) CED(a[2],a[6]) CED(a[3],a[7])
        CED(a[2],a[4]) CED(a[3],a[5])
        CED(a[1],a[2]) CED(a[3],a[4]) CED(a[5],a[6])
        #pragma unroll
        for (int i = 0; i < 8; ++i) dk[8+i] = fminf(dk[8+i], a[i]);
        BMERGE16(dk)
    }

    // cross-chunk merge of the 8 per-chunk top-16 lists
    #pragma unroll
    for (int s = 0; s < KNN; ++s)
        V[(w * KNN + s) * 64 + l] = dk[s];
    __syncthreads();

    for (int c2 = 0; c2 < CH; ++c2) {
        if (c2 == w) continue;
        float v[KNN];
        #pragma unroll
        for (int s2 = 0; s2 < KNN; ++s2)
            v[s2] = V[(c2 * KNN + s2) * 64 + l];
        #pragma unroll
        for (int s = 0; s < KNN; ++s) dk[s] = fminf(dk[s], v[KNN-1-s]);
        BMERGE16(dk)
    }
    const float tthr = dk[KNN-1];
    __syncthreads();            // V dead -> reuse as JL

    // index-recovery rescan of this wave's chunk
    int* JL = (int*)V;
    const int base = w * KNN * 64;
    int cntS = 0, cntT = 0;
    for (int jj = 0; jj < CHL; ++jj) {
        const int j = j0 + jj;
        const float4 c = pb4[j];
        float dot = __fadd_rn(__fadd_rn(__fmul_rn(me.x,c.x),
                                        __fmul_rn(me.y,c.y)),
                              __fmul_rn(me.z,c.z));
        float d2 = __fsub_rn(__fadd_rn(me.w, c.w), __fmul_rn(2.0f, dot));
        d2 = (j == q) ? 1e30f : d2;
        if (d2 <= tthr) {
            if (d2 < tthr) {
                if (cntS + cntT >= KNN) --cntT;
                JL[base + cntS * 64 + l] = j;
                ++cntS;
            } else if (cntS + cntT < KNN) {
                JL[base + (KNN - 1 - cntT) * 64 + l] = j;
                ++cntT;
            }
        }
    }
    CNTS[w * 64 + l] = cntS | (cntT << 16);
    __syncthreads();

    // gather: wave 0, lane l owns query l (strict first, then ties, in
    // (chunk, index) order == global index order -> reference tie-break)
    if (w == 0) {
        int* o = idxws + ((size_t)b * NPTS + q) * KNN;
        int outc = 0;
        for (int c2 = 0; c2 < CH; ++c2) {
            int cs = CNTS[c2 * 64 + l] & 0xffff;
            for (int s2 = 0; s2 < cs && outc < KNN; ++s2)
                o[outc++] = JL[(c2 * KNN + s2) * 64 + l];
        }
        for (int c2 = 0; c2 < CH && outc < KNN; ++c2) {
            int ct = CNTS[c2 * 64 + l] >> 16;
            for (int s2 = 0; s2 < ct && outc < KNN; ++s2)
                o[outc++] = JL[(c2 * KNN + (KNN - 1 - s2)) * 64 + l];
        }
    }
}

// ========================== K3: MFMA edge MLP ==============================
__global__ __launch_bounds__(512) void mlp_kernel(
    const float* __restrict__ x,
    const float* __restrict__ W_edge, const float* __restrict__ b_edge,
    const float* __restrict__ W_nn,   const float* __restrict__ b_nn,
    const int* __restrict__ idxws, float* __restrict__ out)
{
    __shared__ float Z[8 * 16 * 64];     // 32 KB

    const int b    = blockIdx.x >> 4;
    const int qgb  = blockIdx.x & 15;
    const int t    = threadIdx.x;
    const int w    = t >> 6;
    const int lane = t & 63;
    const int c15  = lane & 15;
    const int g    = lane >> 4;

    float* Zw = Z + w * (16 * 64);       // 1024 floats per wave

    const int n0    = b * NPTS + qgb * 128 + w * 16;  // global node base
    const int gbase = b * NPTS;                        // batch start row

    // B-fragments (bf16) + epilogue constants
    int4 Bhi[4], Bd[4], Bn[4];
    #pragma unroll
    for (int f = 0; f < 4; ++f) {
        const int col = 16 * f + c15;
        unsigned ph[4], pd[4], pn[4];
        #pragma unroll
        for (int d = 0; d < 4; ++d) {
            const int k0 = g * 8 + 2 * d;
            float h0 = W_edge[(FIN + k0)     * FOUT + col];
            float h1 = W_edge[(FIN + k0 + 1) * FOUT + col];
            float l0 = W_edge[k0       * FOUT + col] - h0;
            float l1 = W_edge[(k0 + 1) * FOUT + col] - h1;
            float n0f = W_nn[k0       * FOUT + col];
            float n1f = W_nn[(k0 + 1) * FOUT + col];
            ph[d] = bf16pk(h0, h1);
            pd[d] = bf16pk(l0, l1);
            pn[d] = bf16pk(n0f, n1f);
        }
        Bhi[f] = make_int4(ph[0], ph[1], ph[2], ph[3]);
        Bd[f]  = make_int4(pd[0], pd[1], pd[2], pd[3]);
        Bn[f]  = make_int4(pn[0], pn[1], pn[2], pn[3]);
    }
    float beF[4], bnF[4];
    #pragma unroll
    for (int f = 0; f < 4; ++f) {
        beF[f] = b_edge[16 * f + c15];
        bnF[f] = b_nn[16 * f + c15];
    }

    const f32x4 zf = {0.f, 0.f, 0.f, 0.f};

    // Phase 1: base/skip via MFMA over the 16 x_i rows (direct A-frag)
    f32x4 baseF[4], skipF[4];
    {
        const float* rp = x + (size_t)(n0 + c15) * FIN + g * 8;
        float4 v0 = *(const float4*)rp;
        float4 v1 = *(const float4*)(rp + 4);
        int4 pk = make_int4(bf16pk(v0.x, v0.y), bf16pk(v0.z, v0.w),
                            bf16pk(v1.x, v1.y), bf16pk(v1.z, v1.w));
        bf16x8 afi = *(bf16x8*)&pk;
        #pragma unroll
        for (int f = 0; f < 4; ++f) {
            baseF[f] = __builtin_amdgcn_mfma_f32_16x16x32_bf16(
                afi, *(bf16x8*)&Bd[f], zf, 0, 0, 0);
            skipF[f] = __builtin_amdgcn_mfma_f32_16x16x32_bf16(
                afi, *(bf16x8*)&Bn[f], zf, 0, 0, 0);
        }
    }

    // Phase 2: rolled node loop, direct A-frag gather, depth-1 prefetch
    int nb0 = idxws[(size_t)n0 * KNN + c15];
    const float* rpp = x + (size_t)(gbase + nb0) * FIN + g * 8;
    float4 pv0 = *(const float4*)rpp;
    float4 pv1 = *(const float4*)(rpp + 4);

    #pragma unroll 1
    for (int i = 0; i < 16; ++i) {
        float4 c0 = pv0, c1 = pv1;
        if (i < 15) {
            int nb = idxws[(size_t)(n0 + i + 1) * KNN + c15];
            const float* rp = x + (size_t)(gbase + nb) * FIN + g * 8;
            pv0 = *(const float4*)rp;
            pv1 = *(const float4*)(rp + 4);
        }
        int4 pk = make_int4(bf16pk(c0.x, c0.y), bf16pk(c0.z, c0.w),
                            bf16pk(c1.x, c1.y), bf16pk(c1.z, c1.w));
        bf16x8 af = *(bf16x8*)&pk;

        float rmax[4];
        #pragma unroll
        for (int f = 0; f < 4; ++f) {
            f32x4 z = __builtin_amdgcn_mfma_f32_16x16x32_bf16(
                af, *(bf16x8*)&Bhi[f], zf, 0, 0, 0);
            float m = fmaxf(fmaxf(z[0], z[1]), fmaxf(z[2], z[3]));
            m = fmaxf(m, __shfl_xor(m, 16));
            m = fmaxf(m, __shfl_xor(m, 32));
            rmax[f] = m;
        }
        float zv = (g == 0) ? rmax[0] : (g == 1) ? rmax[1]
                 : (g == 2) ? rmax[2] : rmax[3];
        Zw[i * 64 + 16 * g + c15] = zv;
    }

    // Phase 3: epilogue + store (D layout: node=(g*4+reg), col=16f+c15)
    #pragma unroll
    for (int f = 0; f < 4; ++f) {
        #pragma unroll
        for (int reg = 0; reg < 4; ++reg) {
            const int nd = g * 4 + reg;
            float zmax = Zw[nd * 64 + 16 * f + c15];
            float e  = fmaxf(zmax + baseF[f][reg] + beF[f], 0.f);
            float sk = fmaxf(skipF[f][reg] + bnF[f], 0.f);
            out[(size_t)(n0 + nd) * FOUT + 16 * f + c15] = e + sk;
        }
    }
}

// ---------------------------------------------------------------------------
extern "C" void kernel_launch(void* const* d_in, const int* in_sizes, int n_in,
                              void* d_out, int out_size, void* d_ws, size_t ws_size,
                              hipStream_t stream) {
    const float* x      = (const float*)d_in[0];
    const float* pos    = (const float*)d_in[1];
    const float* W_edge = (const float*)d_in[2];
    const float* b_edge = (const float*)d_in[3];
    const float* W_nn   = (const float*)d_in[4];
    const float* b_nn   = (const float*)d_in[5];

    int*    idxws = (int*)d_ws;                                  // 4 MB
    float4* P4    = (float4*)((char*)d_ws + (4u << 20));         // 1 MB
    float*  outp  = (float*)d_out;

    sq_kernel <<<NB * NPTS / 256, 256, 0, stream>>>(pos, P4);
    knn_kernel<<<NB * 32,         512, 0, stream>>>(P4, idxws);
    mlp_kernel<<<NB * 16,         512, 0, stream>>>(x, W_edge, b_edge,
                                                    W_nn, b_nn, idxws, outp);
}

// Round 4
// 215.073 us; speedup vs baseline: 1.1591x; 1.1591x over previous
//
#include <hip/hip_runtime.h>

// Problem constants (from reference)
#define NB     32      // B
#define NPTS   2048    // N
#define KNN    16      // K
#define FIN    32      // F_IN
#define FOUT   64      // F_OUT

typedef __attribute__((ext_vector_type(8))) short bf16x8;
typedef __attribute__((ext_vector_type(4))) float f32x4;

// RNE float->bf16 pack
__device__ inline unsigned bf16pk(float lo, float hi) {
    unsigned a = __float_as_uint(lo), b = __float_as_uint(hi);
    a = (a + 0x7fffu + ((a >> 16) & 1u)) >> 16;
    b = (b + 0x7fffu + ((b >> 16) & 1u)) >> 16;
    return (a & 0xffffu) | (b << 16);
}

// ---------------------------------------------------------------------------
// R4: revert to the PASSING R1 base (linear float4 P4, scalar loads, no
// packed-f32 asm). Two ulp-class chain reductions, applied identically in
// select AND rescan (internal consistency of tthr preserved):
//   dot = fma(z,z', fma(y,y', x*x'))          (3 ops, was 5)
//   d2' = fma(-2, dot, c.w)                   (1 op; me.w dropped — uniform
//                                              per-query shift, order-invariant)
// Self-exclusion hoisted to the single wave/64-range that can contain q
// (control-flow-only change, equivalence audited).
// Rationale: ref=np passes with R1's f32 chain => distance gaps >> f32 ulp
// noise => ulp-level chain changes cannot flip neighbor sets.
// ---------------------------------------------------------------------------

#define CEA(x, y) { float _t = fminf(x, y); y = fmaxf(x, y); x = _t; }
#define CED(x, y) { float _t = fmaxf(x, y); y = fminf(x, y); x = _t; }

#define BMERGE16(dk) \
    CEA(dk[0],dk[8])  CEA(dk[1],dk[9])  CEA(dk[2],dk[10]) CEA(dk[3],dk[11]) \
    CEA(dk[4],dk[12]) CEA(dk[5],dk[13]) CEA(dk[6],dk[14]) CEA(dk[7],dk[15]) \
    CEA(dk[0],dk[4])  CEA(dk[1],dk[5])  CEA(dk[2],dk[6])  CEA(dk[3],dk[7])  \
    CEA(dk[8],dk[12]) CEA(dk[9],dk[13]) CEA(dk[10],dk[14]) CEA(dk[11],dk[15]) \
    CEA(dk[0],dk[2])  CEA(dk[1],dk[3])  CEA(dk[4],dk[6])  CEA(dk[5],dk[7])  \
    CEA(dk[8],dk[10]) CEA(dk[9],dk[11]) CEA(dk[12],dk[14]) CEA(dk[13],dk[15]) \
    CEA(dk[0],dk[1])  CEA(dk[2],dk[3])  CEA(dk[4],dk[5])  CEA(dk[6],dk[7])  \
    CEA(dk[8],dk[9])  CEA(dk[10],dk[11]) CEA(dk[12],dk[13]) CEA(dk[14],dk[15])

// ================= K1: (x,y,z,sq) precompute (R1 verbatim) =================
__global__ __launch_bounds__(256) void sq_kernel(
    const float* __restrict__ pos, float4* __restrict__ P4)
{
    const int i = blockIdx.x * 256 + threadIdx.x;   // 0 .. 65535
    const float px = pos[i*3 + 0];
    const float py = pos[i*3 + 1];
    const float pz = pos[i*3 + 2];
    const float sq = __fadd_rn(__fadd_rn(__fmul_rn(px,px), __fmul_rn(py,py)),
                               __fmul_rn(pz,pz));
    P4[i] = make_float4(px, py, pz, sq);
}

// ========================== K2: exact 16-NN ================================
#define CH   8
#define CHL  (NPTS / CH)    // 256

// shifted distance: d2' = c.w - 2*dot  (per-query order == true d2 order)
#define D2P(C, DST)                                                        \
    {                                                                      \
        float _dot = __fmaf_rn(me.z, (C).z,                                \
                      __fmaf_rn(me.y, (C).y, __fmul_rn(me.x, (C).x)));     \
        DST = __fmaf_rn(-2.0f, _dot, (C).w);                               \
    }

// one batch of 8 candidates starting at JB, merge into dk[]
#define SBATCH(JB, EXCLF)                                                  \
    {                                                                      \
        float a[8];                                                        \
        _Pragma("unroll")                                                  \
        for (int i = 0; i < 8; ++i) {                                      \
            const int j = (JB) + i;                                        \
            const float4 c = pb4[j];                                       \
            float d2;                                                      \
            D2P(c, d2)                                                     \
            a[i] = (EXCLF && j == q) ? 1e30f : d2;                         \
        }                                                                  \
        CED(a[0],a[1]) CED(a[2],a[3]) CED(a[4],a[5]) CED(a[6],a[7])        \
        CED(a[0],a[2]) CED(a[1],a[3]) CED(a[4],a[6]) CED(a[5],a[7])        \
        CED(a[1],a[2]) CED(a[5],a[6])                                      \
        CED(a[0],a[4]) CED(a[1],a[5]) CED(a[2],a[6]) CED(a[3],a[7])        \
        CED(a[2],a[4]) CED(a[3],a[5])                                      \
        CED(a[1],a[2]) CED(a[3],a[4]) CED(a[5],a[6])                       \
        _Pragma("unroll")                                                  \
        for (int i = 0; i < 8; ++i) dk[8+i] = fminf(dk[8+i], a[i]);        \
        BMERGE16(dk)                                                       \
    }

// rescan append (order within chunk = ascending j -> reference tie-break)
#define APP(DD, JJ)                                                        \
    if ((DD) <= tthr) {                                                    \
        if ((DD) < tthr) {                                                 \
            if (cntS + cntT >= KNN) --cntT;                                \
            JL[base + cntS * 64 + l] = (JJ);                               \
            ++cntS;                                                        \
        } else if (cntS + cntT < KNN) {                                    \
            JL[base + (KNN - 1 - cntT) * 64 + l] = (JJ);                   \
            ++cntT;                                                        \
        }                                                                  \
    }

#define RESC(JJ, EXCLF)                                                    \
    {                                                                      \
        const float4 c = pb4[(JJ)];                                        \
        float d2;                                                          \
        D2P(c, d2)                                                         \
        if (EXCLF && (JJ) == q) d2 = 1e30f;                                \
        APP(d2, (JJ))                                                      \
    }

__global__ __launch_bounds__(512, 8) void knn_kernel(
    const float4* __restrict__ P4, int* __restrict__ idxws)
{
    __shared__ float V[CH * KNN * 64];   // 32 KB; reused as int JL
    __shared__ int   CNTS[CH * 64];      // 2 KB

    const int b    = blockIdx.x >> 5;    // 32 blocks per batch
    const int slab = blockIdx.x & 31;    // 64-query slab within batch
    const int t    = threadIdx.x;
    const int w    = __builtin_amdgcn_readfirstlane(t >> 6);  // chunk id
    const int l    = t & 63;

    const float4* __restrict__ pb4 = P4 + (size_t)b * NPTS;

    const int    q  = slab * 64 + l;     // query within batch (0..2047)
    const float4 me = pb4[q];            // me.w unused (shift dropped)

    float dk[KNN];
    #pragma unroll
    for (int s = 0; s < KNN; ++s) dk[s] = 1e30f;

    const int j0  = w * CHL;
    const int exw = slab >> 2;                 // the chunk containing q's
    const int lo  = j0 + (slab & 3) * 64;      // 64-range containing q's

    if (w == exw) {
        for (int jb = j0;      jb < lo;        jb += 8) SBATCH(jb, false)
        for (int jb = lo;      jb < lo + 64;   jb += 8) SBATCH(jb, true)
        for (int jb = lo + 64; jb < j0 + CHL;  jb += 8) SBATCH(jb, false)
    } else {
        for (int jb = j0;      jb < j0 + CHL;  jb += 8) SBATCH(jb, false)
    }

    // cross-chunk merge of the 8 per-chunk top-16 lists
    #pragma unroll
    for (int s = 0; s < KNN; ++s)
        V[(w * KNN + s) * 64 + l] = dk[s];
    __syncthreads();

    for (int c2 = 0; c2 < CH; ++c2) {
        if (c2 == w) continue;
        float v[KNN];
        #pragma unroll
        for (int s2 = 0; s2 < KNN; ++s2)
            v[s2] = V[(c2 * KNN + s2) * 64 + l];
        #pragma unroll
        for (int s = 0; s < KNN; ++s) dk[s] = fminf(dk[s], v[KNN-1-s]);
        BMERGE16(dk)
    }
    const float tthr = dk[KNN-1];
    __syncthreads();            // V dead -> reuse as JL

    // index-recovery rescan of this wave's chunk (identical d2' chain)
    int* JL = (int*)V;
    const int base = w * KNN * 64;
    int cntS = 0, cntT = 0;
    if (w == exw) {
        for (int j = j0;      j < lo;        ++j) RESC(j, false)
        for (int j = lo;      j < lo + 64;   ++j) RESC(j, true)
        for (int j = lo + 64; j < j0 + CHL;  ++j) RESC(j, false)
    } else {
        for (int j = j0;      j < j0 + CHL;  ++j) RESC(j, false)
    }
    CNTS[w * 64 + l] = cntS | (cntT << 16);
    __syncthreads();

    // gather: wave 0, lane l owns query l (strict first, then ties, in
    // (chunk, index) order == global index order -> reference tie-break)
    if (w == 0) {
        int* o = idxws + ((size_t)b * NPTS + q) * KNN;
        int outc = 0;
        for (int c2 = 0; c2 < CH; ++c2) {
            int cs = CNTS[c2 * 64 + l] & 0xffff;
            for (int s2 = 0; s2 < cs && outc < KNN; ++s2)
                o[outc++] = JL[(c2 * KNN + s2) * 64 + l];
        }
        for (int c2 = 0; c2 < CH && outc < KNN; ++c2) {
            int ct = CNTS[c2 * 64 + l] >> 16;
            for (int s2 = 0; s2 < ct && outc < KNN; ++s2)
                o[outc++] = JL[(c2 * KNN + (KNN - 1 - s2)) * 64 + l];
        }
    }
}

// ========================== K3: MFMA edge MLP ==============================
__global__ __launch_bounds__(512) void mlp_kernel(
    const float* __restrict__ x,
    const float* __restrict__ W_edge, const float* __restrict__ b_edge,
    const float* __restrict__ W_nn,   const float* __restrict__ b_nn,
    const int* __restrict__ idxws, float* __restrict__ out)
{
    __shared__ float Z[8 * 16 * 64];     // 32 KB

    const int b    = blockIdx.x >> 4;
    const int qgb  = blockIdx.x & 15;
    const int t    = threadIdx.x;
    const int w    = t >> 6;
    const int lane = t & 63;
    const int c15  = lane & 15;
    const int g    = lane >> 4;

    float* Zw = Z + w * (16 * 64);       // 1024 floats per wave

    const int n0    = b * NPTS + qgb * 128 + w * 16;  // global node base
    const int gbase = b * NPTS;                        // batch start row

    // B-fragments (bf16) + epilogue constants
    int4 Bhi[4], Bd[4], Bn[4];
    #pragma unroll
    for (int f = 0; f < 4; ++f) {
        const int col = 16 * f + c15;
        unsigned ph[4], pd[4], pn[4];
        #pragma unroll
        for (int d = 0; d < 4; ++d) {
            const int k0 = g * 8 + 2 * d;
            float h0 = W_edge[(FIN + k0)     * FOUT + col];
            float h1 = W_edge[(FIN + k0 + 1) * FOUT + col];
            float l0 = W_edge[k0       * FOUT + col] - h0;
            float l1 = W_edge[(k0 + 1) * FOUT + col] - h1;
            float n0f = W_nn[k0       * FOUT + col];
            float n1f = W_nn[(k0 + 1) * FOUT + col];
            ph[d] = bf16pk(h0, h1);
            pd[d] = bf16pk(l0, l1);
            pn[d] = bf16pk(n0f, n1f);
        }
        Bhi[f] = make_int4(ph[0], ph[1], ph[2], ph[3]);
        Bd[f]  = make_int4(pd[0], pd[1], pd[2], pd[3]);
        Bn[f]  = make_int4(pn[0], pn[1], pn[2], pn[3]);
    }
    float beF[4], bnF[4];
    #pragma unroll
    for (int f = 0; f < 4; ++f) {
        beF[f] = b_edge[16 * f + c15];
        bnF[f] = b_nn[16 * f + c15];
    }

    const f32x4 zf = {0.f, 0.f, 0.f, 0.f};

    // Phase 1: base/skip via MFMA over the 16 x_i rows (direct A-frag)
    f32x4 baseF[4], skipF[4];
    {
        const float* rp = x + (size_t)(n0 + c15) * FIN + g * 8;
        float4 v0 = *(const float4*)rp;
        float4 v1 = *(const float4*)(rp + 4);
        int4 pk = make_int4(bf16pk(v0.x, v0.y), bf16pk(v0.z, v0.w),
                            bf16pk(v1.x, v1.y), bf16pk(v1.z, v1.w));
        bf16x8 afi = *(bf16x8*)&pk;
        #pragma unroll
        for (int f = 0; f < 4; ++f) {
            baseF[f] = __builtin_amdgcn_mfma_f32_16x16x32_bf16(
                afi, *(bf16x8*)&Bd[f], zf, 0, 0, 0);
            skipF[f] = __builtin_amdgcn_mfma_f32_16x16x32_bf16(
                afi, *(bf16x8*)&Bn[f], zf, 0, 0, 0);
        }
    }

    // Phase 2: rolled node loop, direct A-frag gather, depth-1 prefetch
    int nb0 = idxws[(size_t)n0 * KNN + c15];
    const float* rpp = x + (size_t)(gbase + nb0) * FIN + g * 8;
    float4 pv0 = *(const float4*)rpp;
    float4 pv1 = *(const float4*)(rpp + 4);

    #pragma unroll 1
    for (int i = 0; i < 16; ++i) {
        float4 c0 = pv0, c1 = pv1;
        if (i < 15) {
            int nb = idxws[(size_t)(n0 + i + 1) * KNN + c15];
            const float* rp = x + (size_t)(gbase + nb) * FIN + g * 8;
            pv0 = *(const float4*)rp;
            pv1 = *(const float4*)(rp + 4);
        }
        int4 pk = make_int4(bf16pk(c0.x, c0.y), bf16pk(c0.z, c0.w),
                            bf16pk(c1.x, c1.y), bf16pk(c1.z, c1.w));
        bf16x8 af = *(bf16x8*)&pk;

        float rmax[4];
        #pragma unroll
        for (int f = 0; f < 4; ++f) {
            f32x4 z = __builtin_amdgcn_mfma_f32_16x16x32_bf16(
                af, *(bf16x8*)&Bhi[f], zf, 0, 0, 0);
            float m = fmaxf(fmaxf(z[0], z[1]), fmaxf(z[2], z[3]));
            m = fmaxf(m, __shfl_xor(m, 16));
            m = fmaxf(m, __shfl_xor(m, 32));
            rmax[f] = m;
        }
        float zv = (g == 0) ? rmax[0] : (g == 1) ? rmax[1]
                 : (g == 2) ? rmax[2] : rmax[3];
        Zw[i * 64 + 16 * g + c15] = zv;
    }

    // Phase 3: epilogue + store (D layout: node=(g*4+reg), col=16f+c15)
    #pragma unroll
    for (int f = 0; f < 4; ++f) {
        #pragma unroll
        for (int reg = 0; reg < 4; ++reg) {
            const int nd = g * 4 + reg;
            float zmax = Zw[nd * 64 + 16 * f + c15];
            float e  = fmaxf(zmax + baseF[f][reg] + beF[f], 0.f);
            float sk = fmaxf(skipF[f][reg] + bnF[f], 0.f);
            out[(size_t)(n0 + nd) * FOUT + 16 * f + c15] = e + sk;
        }
    }
}

// ---------------------------------------------------------------------------
extern "C" void kernel_launch(void* const* d_in, const int* in_sizes, int n_in,
                              void* d_out, int out_size, void* d_ws, size_t ws_size,
                              hipStream_t stream) {
    const float* x      = (const float*)d_in[0];
    const float* pos    = (const float*)d_in[1];
    const float* W_edge = (const float*)d_in[2];
    const float* b_edge = (const float*)d_in[3];
    const float* W_nn   = (const float*)d_in[4];
    const float* b_nn   = (const float*)d_in[5];

    int*    idxws = (int*)d_ws;                                  // 4 MB
    float4* P4    = (float4*)((char*)d_ws + (4u << 20));         // 1 MB
    float*  outp  = (float*)d_out;

    sq_kernel <<<NB * NPTS / 256, 256, 0, stream>>>(pos, P4);
    knn_kernel<<<NB * 32,         512, 0, stream>>>(P4, idxws);
    mlp_kernel<<<NB * 16,         512, 0, stream>>>(x, W_edge, b_edge,
                                                    W_nn, b_nn, idxws, outp);
}

// Round 5
// 205.870 us; speedup vs baseline: 1.2110x; 1.0447x over previous
//
#include <hip/hip_runtime.h>

// Problem constants (from reference)
#define NB     32      // B
#define NPTS   2048    // N
#define KNN    16      // K
#define FIN    32      // F_IN
#define FOUT   64      // F_OUT

typedef __attribute__((ext_vector_type(8))) short bf16x8;
typedef __attribute__((ext_vector_type(4))) float f32x4;

// RNE float->bf16 pack
__device__ inline unsigned bf16pk(float lo, float hi) {
    unsigned a = __float_as_uint(lo), b = __float_as_uint(hi);
    a = (a + 0x7fffu + ((a >> 16) & 1u)) >> 16;
    b = (b + 0x7fffu + ((b >> 16) & 1u)) >> 16;
    return (a & 0xffffu) | (b << 16);
}

// ---------------------------------------------------------------------------
// R5: fuse MLP into the knn kernel (2 dispatches total).
//  - Phase A == R4 verbatim (FMA-contracted shifted distance, exclusion
//    hoisting, identical tie machinery), except gather writes neighbor
//    lists to LDS IDX[64][16] instead of global idxws (no other consumer).
//    Select pass processes 16 candidates per iteration as two independent
//    sort-8s merged in the ORIGINAL order -> dk bit-identical, 2x ILP.
//  - Phase B: edge MLP for this block's 64 nodes. 8 waves = 4 node-groups
//    x 2 f-pairs (halves per-wave B-frag registers vs the 128-node kernel).
//    Zw aliases dead JL; wave-pair writes disjoint Zw columns and each wave
//    reads only its own columns -> no extra barrier inside phase B.
//  LDS: V 32K + CNTS 2K + IDX 4K = 38912 B -> 4 blocks/CU retained.
// ---------------------------------------------------------------------------

#define CEA(x, y) { float _t = fminf(x, y); y = fmaxf(x, y); x = _t; }
#define CED(x, y) { float _t = fmaxf(x, y); y = fminf(x, y); x = _t; }

#define BMERGE16(dk) \
    CEA(dk[0],dk[8])  CEA(dk[1],dk[9])  CEA(dk[2],dk[10]) CEA(dk[3],dk[11]) \
    CEA(dk[4],dk[12]) CEA(dk[5],dk[13]) CEA(dk[6],dk[14]) CEA(dk[7],dk[15]) \
    CEA(dk[0],dk[4])  CEA(dk[1],dk[5])  CEA(dk[2],dk[6])  CEA(dk[3],dk[7])  \
    CEA(dk[8],dk[12]) CEA(dk[9],dk[13]) CEA(dk[10],dk[14]) CEA(dk[11],dk[15]) \
    CEA(dk[0],dk[2])  CEA(dk[1],dk[3])  CEA(dk[4],dk[6])  CEA(dk[5],dk[7])  \
    CEA(dk[8],dk[10]) CEA(dk[9],dk[11]) CEA(dk[12],dk[14]) CEA(dk[13],dk[15]) \
    CEA(dk[0],dk[1])  CEA(dk[2],dk[3])  CEA(dk[4],dk[5])  CEA(dk[6],dk[7])  \
    CEA(dk[8],dk[9])  CEA(dk[10],dk[11]) CEA(dk[12],dk[13]) CEA(dk[14],dk[15])

#define NET8(a) \
    CED(a[0],a[1]) CED(a[2],a[3]) CED(a[4],a[5]) CED(a[6],a[7]) \
    CED(a[0],a[2]) CED(a[1],a[3]) CED(a[4],a[6]) CED(a[5],a[7]) \
    CED(a[1],a[2]) CED(a[5],a[6]) \
    CED(a[0],a[4]) CED(a[1],a[5]) CED(a[2],a[6]) CED(a[3],a[7]) \
    CED(a[2],a[4]) CED(a[3],a[5]) \
    CED(a[1],a[2]) CED(a[3],a[4]) CED(a[5],a[6])

// ================= K1: (x,y,z,sq) precompute (verbatim) ====================
__global__ __launch_bounds__(256) void sq_kernel(
    const float* __restrict__ pos, float4* __restrict__ P4)
{
    const int i = blockIdx.x * 256 + threadIdx.x;   // 0 .. 65535
    const float px = pos[i*3 + 0];
    const float py = pos[i*3 + 1];
    const float pz = pos[i*3 + 2];
    const float sq = __fadd_rn(__fadd_rn(__fmul_rn(px,px), __fmul_rn(py,py)),
                               __fmul_rn(pz,pz));
    P4[i] = make_float4(px, py, pz, sq);
}

// ==================== K2: fused exact 16-NN + edge MLP =====================
#define CH   8
#define CHL  (NPTS / CH)    // 256

// shifted distance: d2' = c.w - 2*dot  (per-query order == true d2 order)
#define D2P(C, DST)                                                        \
    {                                                                      \
        float _dot = __fmaf_rn(me.z, (C).z,                                \
                      __fmaf_rn(me.y, (C).y, __fmul_rn(me.x, (C).x)));     \
        DST = __fmaf_rn(-2.0f, _dot, (C).w);                               \
    }

// 16 candidates: two independent sort-8s, merged in the original order
#define SBATCH2(JB, EXCLF)                                                 \
    {                                                                      \
        float a[8], a2[8];                                                 \
        _Pragma("unroll")                                                  \
        for (int i = 0; i < 8; ++i) {                                      \
            const int j = (JB) + i;                                        \
            const float4 c = pb4[j];                                       \
            float d2;                                                      \
            D2P(c, d2)                                                     \
            a[i] = (EXCLF && j == q) ? 1e30f : d2;                         \
        }                                                                  \
        _Pragma("unroll")                                                  \
        for (int i = 0; i < 8; ++i) {                                      \
            const int j = (JB) + 8 + i;                                    \
            const float4 c = pb4[j];                                       \
            float d2;                                                      \
            D2P(c, d2)                                                     \
            a2[i] = (EXCLF && j == q) ? 1e30f : d2;                        \
        }                                                                  \
        NET8(a)                                                            \
        NET8(a2)                                                           \
        _Pragma("unroll")                                                  \
        for (int i = 0; i < 8; ++i) dk[8+i] = fminf(dk[8+i], a[i]);        \
        BMERGE16(dk)                                                       \
        _Pragma("unroll")                                                  \
        for (int i = 0; i < 8; ++i) dk[8+i] = fminf(dk[8+i], a2[i]);       \
        BMERGE16(dk)                                                       \
    }

// rescan append (order within chunk = ascending j -> reference tie-break)
#define APP(DD, JJ)                                                        \
    if ((DD) <= tthr) {                                                    \
        if ((DD) < tthr) {                                                 \
            if (cntS + cntT >= KNN) --cntT;                                \
            JL[base + cntS * 64 + l] = (JJ);                               \
            ++cntS;                                                        \
        } else if (cntS + cntT < KNN) {                                    \
            JL[base + (KNN - 1 - cntT) * 64 + l] = (JJ);                   \
            ++cntT;                                                        \
        }                                                                  \
    }

#define RESC(JJ, EXCLF)                                                    \
    {                                                                      \
        const float4 c = pb4[(JJ)];                                        \
        float d2;                                                          \
        D2P(c, d2)                                                         \
        if (EXCLF && (JJ) == q) d2 = 1e30f;                                \
        APP(d2, (JJ))                                                      \
    }

__global__ __launch_bounds__(512, 8) void knn_mlp_kernel(
    const float4* __restrict__ P4, const float* __restrict__ x,
    const float* __restrict__ W_edge, const float* __restrict__ b_edge,
    const float* __restrict__ W_nn,   const float* __restrict__ b_nn,
    float* __restrict__ out)
{
    __shared__ float V[CH * KNN * 64];   // 32 KB; -> int JL -> Zw (phase B)
    __shared__ int   CNTS[CH * 64];      // 2 KB
    __shared__ int   IDX[64 * KNN];      // 4 KB: neighbor lists, 64 nodes

    const int b    = blockIdx.x >> 5;    // 32 blocks per batch
    const int slab = blockIdx.x & 31;    // 64-query slab within batch
    const int t    = threadIdx.x;
    const int w    = __builtin_amdgcn_readfirstlane(t >> 6);  // chunk id
    const int l    = t & 63;

    // ======================= Phase A: exact 16-NN ==========================
    {
        const float4* __restrict__ pb4 = P4 + (size_t)b * NPTS;

        const int    q  = slab * 64 + l;     // query within batch (0..2047)
        const float4 me = pb4[q];            // me.w unused (shift dropped)

        float dk[KNN];
        #pragma unroll
        for (int s = 0; s < KNN; ++s) dk[s] = 1e30f;

        const int j0  = w * CHL;
        const int exw = slab >> 2;                 // chunk containing q's
        const int lo  = j0 + (slab & 3) * 64;      // 64-range containing q's

        if (w == exw) {
            for (int jb = j0;      jb < lo;        jb += 16) SBATCH2(jb, false)
            for (int jb = lo;      jb < lo + 64;   jb += 16) SBATCH2(jb, true)
            for (int jb = lo + 64; jb < j0 + CHL;  jb += 16) SBATCH2(jb, false)
        } else {
            for (int jb = j0;      jb < j0 + CHL;  jb += 16) SBATCH2(jb, false)
        }

        // cross-chunk merge of the 8 per-chunk top-16 lists
        #pragma unroll
        for (int s = 0; s < KNN; ++s)
            V[(w * KNN + s) * 64 + l] = dk[s];
        __syncthreads();

        for (int c2 = 0; c2 < CH; ++c2) {
            if (c2 == w) continue;
            float v[KNN];
            #pragma unroll
            for (int s2 = 0; s2 < KNN; ++s2)
                v[s2] = V[(c2 * KNN + s2) * 64 + l];
            #pragma unroll
            for (int s = 0; s < KNN; ++s) dk[s] = fminf(dk[s], v[KNN-1-s]);
            BMERGE16(dk)
        }
        const float tthr = dk[KNN-1];
        __syncthreads();            // V dead -> reuse as JL

        // index-recovery rescan of this wave's chunk (identical d2' chain)
        int* JL = (int*)V;
        const int base = w * KNN * 64;
        int cntS = 0, cntT = 0;
        if (w == exw) {
            for (int j = j0;      j < lo;        ++j) RESC(j, false)
            for (int j = lo;      j < lo + 64;   ++j) RESC(j, true)
            for (int j = lo + 64; j < j0 + CHL;  ++j) RESC(j, false)
        } else {
            for (int j = j0;      j < j0 + CHL;  ++j) RESC(j, false)
        }
        CNTS[w * 64 + l] = cntS | (cntT << 16);
        __syncthreads();

        // gather: wave 0, lane l owns query l (strict first, then ties, in
        // (chunk, index) order == global index order -> reference tie-break)
        if (w == 0) {
            int outc = 0;
            for (int c2 = 0; c2 < CH; ++c2) {
                int cs = CNTS[c2 * 64 + l] & 0xffff;
                for (int s2 = 0; s2 < cs && outc < KNN; ++s2)
                    IDX[l * KNN + outc++] = JL[(c2 * KNN + s2) * 64 + l];
            }
            for (int c2 = 0; c2 < CH && outc < KNN; ++c2) {
                int ct = CNTS[c2 * 64 + l] >> 16;
                for (int s2 = 0; s2 < ct && outc < KNN; ++s2)
                    IDX[l * KNN + outc++] =
                        JL[(c2 * KNN + (KNN - 1 - s2)) * 64 + l];
            }
        }
        __syncthreads();            // IDX visible; JL dead below
    }

    // ======================= Phase B: MFMA edge MLP ========================
    // 8 waves = 4 node-groups (16 nodes each) x 2 f-pairs.
    {
        const int c15 = l & 15;
        const int g   = l >> 4;
        const int ng  = w & 3;           // node group 0..3
        const int f0  = (w >> 2) * 2;    // f-pair base: 0 or 2

        float* Zw = V + ng * (16 * 64);  // wave-pair shares rows, disjoint cols

        const int n0    = b * NPTS + slab * 64 + ng * 16;  // global node base
        const int gbase = b * NPTS;                         // batch start row

        // B-fragments (bf16) + epilogue constants, 2 f-slices per wave
        int4 Bhi[2], Bd[2], Bn[2];
        #pragma unroll
        for (int ff = 0; ff < 2; ++ff) {
            const int col = 16 * (f0 + ff) + c15;
            unsigned ph[4], pd[4], pn[4];
            #pragma unroll
            for (int d = 0; d < 4; ++d) {
                const int k0 = g * 8 + 2 * d;
                float h0 = W_edge[(FIN + k0)     * FOUT + col];
                float h1 = W_edge[(FIN + k0 + 1) * FOUT + col];
                float l0 = W_edge[k0       * FOUT + col] - h0;
                float l1 = W_edge[(k0 + 1) * FOUT + col] - h1;
                float n0f = W_nn[k0       * FOUT + col];
                float n1f = W_nn[(k0 + 1) * FOUT + col];
                ph[d] = bf16pk(h0, h1);
                pd[d] = bf16pk(l0, l1);
                pn[d] = bf16pk(n0f, n1f);
            }
            Bhi[ff] = make_int4(ph[0], ph[1], ph[2], ph[3]);
            Bd[ff]  = make_int4(pd[0], pd[1], pd[2], pd[3]);
            Bn[ff]  = make_int4(pn[0], pn[1], pn[2], pn[3]);
        }
        float beF[2], bnF[2];
        #pragma unroll
        for (int ff = 0; ff < 2; ++ff) {
            beF[ff] = b_edge[16 * (f0 + ff) + c15];
            bnF[ff] = b_nn[16 * (f0 + ff) + c15];
        }

        const f32x4 zf = {0.f, 0.f, 0.f, 0.f};

        // Phase 1: base/skip via MFMA over the 16 x_i rows (direct A-frag)
        f32x4 baseF[2], skipF[2];
        {
            const float* rp = x + (size_t)(n0 + c15) * FIN + g * 8;
            float4 v0 = *(const float4*)rp;
            float4 v1 = *(const float4*)(rp + 4);
            int4 pk = make_int4(bf16pk(v0.x, v0.y), bf16pk(v0.z, v0.w),
                                bf16pk(v1.x, v1.y), bf16pk(v1.z, v1.w));
            bf16x8 afi = *(bf16x8*)&pk;
            #pragma unroll
            for (int ff = 0; ff < 2; ++ff) {
                baseF[ff] = __builtin_amdgcn_mfma_f32_16x16x32_bf16(
                    afi, *(bf16x8*)&Bd[ff], zf, 0, 0, 0);
                skipF[ff] = __builtin_amdgcn_mfma_f32_16x16x32_bf16(
                    afi, *(bf16x8*)&Bn[ff], zf, 0, 0, 0);
            }
        }

        // Phase 2: rolled node loop, neighbor A-frag gather, depth-1 prefetch
        int nb0 = IDX[(ng * 16 + 0) * KNN + c15];
        const float* rpp = x + (size_t)(gbase + nb0) * FIN + g * 8;
        float4 pv0 = *(const float4*)rpp;
        float4 pv1 = *(const float4*)(rpp + 4);

        #pragma unroll 1
        for (int i = 0; i < 16; ++i) {
            float4 c0 = pv0, c1 = pv1;
            if (i < 15) {
                int nb = IDX[(ng * 16 + i + 1) * KNN + c15];
                const float* rp = x + (size_t)(gbase + nb) * FIN + g * 8;
                pv0 = *(const float4*)rp;
                pv1 = *(const float4*)(rp + 4);
            }
            int4 pk = make_int4(bf16pk(c0.x, c0.y), bf16pk(c0.z, c0.w),
                                bf16pk(c1.x, c1.y), bf16pk(c1.z, c1.w));
            bf16x8 af = *(bf16x8*)&pk;

            float rmax[2];
            #pragma unroll
            for (int ff = 0; ff < 2; ++ff) {
                f32x4 z = __builtin_amdgcn_mfma_f32_16x16x32_bf16(
                    af, *(bf16x8*)&Bhi[ff], zf, 0, 0, 0);
                float m = fmaxf(fmaxf(z[0], z[1]), fmaxf(z[2], z[3]));
                m = fmaxf(m, __shfl_xor(m, 16));
                m = fmaxf(m, __shfl_xor(m, 32));
                rmax[ff] = m;
            }
            if (g < 2)
                Zw[i * 64 + 16 * (f0 + g) + c15] = (g == 0) ? rmax[0] : rmax[1];
        }

        // Phase 3: epilogue + store (D layout: node=(g*4+reg), col=16f+c15)
        #pragma unroll
        for (int ff = 0; ff < 2; ++ff) {
            #pragma unroll
            for (int reg = 0; reg < 4; ++reg) {
                const int nd = g * 4 + reg;
                float zmax = Zw[nd * 64 + 16 * (f0 + ff) + c15];
                float e  = fmaxf(zmax + baseF[ff][reg] + beF[ff], 0.f);
                float sk = fmaxf(skipF[ff][reg] + bnF[ff], 0.f);
                out[(size_t)(n0 + nd) * FOUT + 16 * (f0 + ff) + c15] = e + sk;
            }
        }
    }
}

// ---------------------------------------------------------------------------
extern "C" void kernel_launch(void* const* d_in, const int* in_sizes, int n_in,
                              void* d_out, int out_size, void* d_ws, size_t ws_size,
                              hipStream_t stream) {
    const float* x      = (const float*)d_in[0];
    const float* pos    = (const float*)d_in[1];
    const float* W_edge = (const float*)d_in[2];
    const float* b_edge = (const float*)d_in[3];
    const float* W_nn   = (const float*)d_in[4];
    const float* b_nn   = (const float*)d_in[5];

    float4* P4   = (float4*)d_ws;       // 1 MB
    float*  outp = (float*)d_out;

    sq_kernel     <<<NB * NPTS / 256, 256, 0, stream>>>(pos, P4);
    knn_mlp_kernel<<<NB * 32,         512, 0, stream>>>(P4, x, W_edge, b_edge,
                                                        W_nn, b_nn, outp);
}

// Round 6
// 204.671 us; speedup vs baseline: 1.2180x; 1.0059x over previous
//
#include <hip/hip_runtime.h>

// Problem constants (from reference)
#define NB     32      // B
#define NPTS   2048    // N
#define KNN    16      // K
#define FIN    32      // F_IN
#define FOUT   64      // F_OUT

typedef __attribute__((ext_vector_type(8))) short bf16x8;
typedef __attribute__((ext_vector_type(4))) float f32x4;

// RNE float->bf16 pack
__device__ inline unsigned bf16pk(float lo, float hi) {
    unsigned a = __float_as_uint(lo), b = __float_as_uint(hi);
    a = (a + 0x7fffu + ((a >> 16) & 1u)) >> 16;
    b = (b + 0x7fffu + ((b >> 16) & 1u)) >> 16;
    return (a & 0xffffu) | (b << 16);
}

// ---------------------------------------------------------------------------
// R6: phase-B restructure — gather each node ONCE.
//  R5's phase B split FOUT across wave-pairs, so every node's neighbor
//  gather (16 rows x 32 floats) was loaded by TWO waves: FETCH 39 MB,
//  latency-bound tail (~24us). New structure:
//   B1: base/skip for all 64 nodes via 32 MFMAs (wave = 16-node group x
//       2 f-slices); E = base+b_edge, S = relu(skip+b_nn) stashed in LDS
//       (stride 66 -> only free 2-way bank conflicts).
//   B2: wave = 8 nodes x ALL 4 f-slices. Per node: one gather, 4 MFMAs,
//       reduce, inline epilogue reading E/S, coalesced 64-lane store.
//       Registers: Bhi[4]=16 VGPR + depth-1 prefetch -> fits 64-VGPR cap.
//  Phase A (exact kNN, FMA-contracted shifted distance, tie machinery)
//  is byte-for-byte unchanged from the verified R5.
//  LDS: one 38912 B arena; E/S (33792 B) alias dead V+CNTS, IDX kept.
// ---------------------------------------------------------------------------

#define CEA(x, y) { float _t = fminf(x, y); y = fmaxf(x, y); x = _t; }
#define CED(x, y) { float _t = fmaxf(x, y); y = fminf(x, y); x = _t; }

#define BMERGE16(dk) \
    CEA(dk[0],dk[8])  CEA(dk[1],dk[9])  CEA(dk[2],dk[10]) CEA(dk[3],dk[11]) \
    CEA(dk[4],dk[12]) CEA(dk[5],dk[13]) CEA(dk[6],dk[14]) CEA(dk[7],dk[15]) \
    CEA(dk[0],dk[4])  CEA(dk[1],dk[5])  CEA(dk[2],dk[6])  CEA(dk[3],dk[7])  \
    CEA(dk[8],dk[12]) CEA(dk[9],dk[13]) CEA(dk[10],dk[14]) CEA(dk[11],dk[15]) \
    CEA(dk[0],dk[2])  CEA(dk[1],dk[3])  CEA(dk[4],dk[6])  CEA(dk[5],dk[7])  \
    CEA(dk[8],dk[10]) CEA(dk[9],dk[11]) CEA(dk[12],dk[14]) CEA(dk[13],dk[15]) \
    CEA(dk[0],dk[1])  CEA(dk[2],dk[3])  CEA(dk[4],dk[5])  CEA(dk[6],dk[7])  \
    CEA(dk[8],dk[9])  CEA(dk[10],dk[11]) CEA(dk[12],dk[13]) CEA(dk[14],dk[15])

#define NET8(a) \
    CED(a[0],a[1]) CED(a[2],a[3]) CED(a[4],a[5]) CED(a[6],a[7]) \
    CED(a[0],a[2]) CED(a[1],a[3]) CED(a[4],a[6]) CED(a[5],a[7]) \
    CED(a[1],a[2]) CED(a[5],a[6]) \
    CED(a[0],a[4]) CED(a[1],a[5]) CED(a[2],a[6]) CED(a[3],a[7]) \
    CED(a[2],a[4]) CED(a[3],a[5]) \
    CED(a[1],a[2]) CED(a[3],a[4]) CED(a[5],a[6])

// ================= K1: (x,y,z,sq) precompute (verbatim) ====================
__global__ __launch_bounds__(256) void sq_kernel(
    const float* __restrict__ pos, float4* __restrict__ P4)
{
    const int i = blockIdx.x * 256 + threadIdx.x;   // 0 .. 65535
    const float px = pos[i*3 + 0];
    const float py = pos[i*3 + 1];
    const float pz = pos[i*3 + 2];
    const float sq = __fadd_rn(__fadd_rn(__fmul_rn(px,px), __fmul_rn(py,py)),
                               __fmul_rn(pz,pz));
    P4[i] = make_float4(px, py, pz, sq);
}

// ==================== K2: fused exact 16-NN + edge MLP =====================
#define CH   8
#define CHL  (NPTS / CH)    // 256

// shifted distance: d2' = c.w - 2*dot  (per-query order == true d2 order)
#define D2P(C, DST)                                                        \
    {                                                                      \
        float _dot = __fmaf_rn(me.z, (C).z,                                \
                      __fmaf_rn(me.y, (C).y, __fmul_rn(me.x, (C).x)));     \
        DST = __fmaf_rn(-2.0f, _dot, (C).w);                               \
    }

// 16 candidates: two independent sort-8s, merged in the original order
#define SBATCH2(JB, EXCLF)                                                 \
    {                                                                      \
        float a[8], a2[8];                                                 \
        _Pragma("unroll")                                                  \
        for (int i = 0; i < 8; ++i) {                                      \
            const int j = (JB) + i;                                        \
            const float4 c = pb4[j];                                       \
            float d2;                                                      \
            D2P(c, d2)                                                     \
            a[i] = (EXCLF && j == q) ? 1e30f : d2;                         \
        }                                                                  \
        _Pragma("unroll")                                                  \
        for (int i = 0; i < 8; ++i) {                                      \
            const int j = (JB) + 8 + i;                                    \
            const float4 c = pb4[j];                                       \
            float d2;                                                      \
            D2P(c, d2)                                                     \
            a2[i] = (EXCLF && j == q) ? 1e30f : d2;                        \
        }                                                                  \
        NET8(a)                                                            \
        NET8(a2)                                                           \
        _Pragma("unroll")                                                  \
        for (int i = 0; i < 8; ++i) dk[8+i] = fminf(dk[8+i], a[i]);        \
        BMERGE16(dk)                                                       \
        _Pragma("unroll")                                                  \
        for (int i = 0; i < 8; ++i) dk[8+i] = fminf(dk[8+i], a2[i]);       \
        BMERGE16(dk)                                                       \
    }

// rescan append (order within chunk = ascending j -> reference tie-break)
#define APP(DD, JJ)                                                        \
    if ((DD) <= tthr) {                                                    \
        if ((DD) < tthr) {                                                 \
            if (cntS + cntT >= KNN) --cntT;                                \
            JL[base + cntS * 64 + l] = (JJ);                               \
            ++cntS;                                                        \
        } else if (cntS + cntT < KNN) {                                    \
            JL[base + (KNN - 1 - cntT) * 64 + l] = (JJ);                   \
            ++cntT;                                                        \
        }                                                                  \
    }

#define RESC(JJ, EXCLF)                                                    \
    {                                                                      \
        const float4 c = pb4[(JJ)];                                        \
        float d2;                                                          \
        D2P(c, d2)                                                         \
        if (EXCLF && (JJ) == q) d2 = 1e30f;                                \
        APP(d2, (JJ))                                                      \
    }

#define ESTRIDE 66   // padded row stride for E/S (66 % 32 spreads g over banks)

__global__ __launch_bounds__(512, 8) void knn_mlp_kernel(
    const float4* __restrict__ P4, const float* __restrict__ x,
    const float* __restrict__ W_edge, const float* __restrict__ b_edge,
    const float* __restrict__ W_nn,   const float* __restrict__ b_nn,
    float* __restrict__ out)
{
    // LDS arena: phase A: [V 32768][CNTS 2048][IDX 4096]
    //            phase B: [E 16896][S 16896][IDX 4096]  (E/S alias V+CNTS)
    __shared__ __attribute__((aligned(16))) char smem[38912];
    float* V    = (float*)smem;
    int*   CNTS = (int*)(smem + 32768);
    int*   IDX  = (int*)(smem + 34816);

    const int b    = blockIdx.x >> 5;    // 32 blocks per batch
    const int slab = blockIdx.x & 31;    // 64-query slab within batch
    const int t    = threadIdx.x;
    const int w    = __builtin_amdgcn_readfirstlane(t >> 6);  // chunk id
    const int l    = t & 63;

    // ======================= Phase A: exact 16-NN ==========================
    {
        const float4* __restrict__ pb4 = P4 + (size_t)b * NPTS;

        const int    q  = slab * 64 + l;     // query within batch (0..2047)
        const float4 me = pb4[q];            // me.w unused (shift dropped)

        float dk[KNN];
        #pragma unroll
        for (int s = 0; s < KNN; ++s) dk[s] = 1e30f;

        const int j0  = w * CHL;
        const int exw = slab >> 2;                 // chunk containing q's
        const int lo  = j0 + (slab & 3) * 64;      // 64-range containing q's

        if (w == exw) {
            for (int jb = j0;      jb < lo;        jb += 16) SBATCH2(jb, false)
            for (int jb = lo;      jb < lo + 64;   jb += 16) SBATCH2(jb, true)
            for (int jb = lo + 64; jb < j0 + CHL;  jb += 16) SBATCH2(jb, false)
        } else {
            for (int jb = j0;      jb < j0 + CHL;  jb += 16) SBATCH2(jb, false)
        }

        // cross-chunk merge of the 8 per-chunk top-16 lists
        #pragma unroll
        for (int s = 0; s < KNN; ++s)
            V[(w * KNN + s) * 64 + l] = dk[s];
        __syncthreads();

        for (int c2 = 0; c2 < CH; ++c2) {
            if (c2 == w) continue;
            float v[KNN];
            #pragma unroll
            for (int s2 = 0; s2 < KNN; ++s2)
                v[s2] = V[(c2 * KNN + s2) * 64 + l];
            #pragma unroll
            for (int s = 0; s < KNN; ++s) dk[s] = fminf(dk[s], v[KNN-1-s]);
            BMERGE16(dk)
        }
        const float tthr = dk[KNN-1];
        __syncthreads();            // V dead -> reuse as JL

        // index-recovery rescan of this wave's chunk (identical d2' chain)
        int* JL = (int*)V;
        const int base = w * KNN * 64;
        int cntS = 0, cntT = 0;
        if (w == exw) {
            for (int j = j0;      j < lo;        ++j) RESC(j, false)
            for (int j = lo;      j < lo + 64;   ++j) RESC(j, true)
            for (int j = lo + 64; j < j0 + CHL;  ++j) RESC(j, false)
        } else {
            for (int j = j0;      j < j0 + CHL;  ++j) RESC(j, false)
        }
        CNTS[w * 64 + l] = cntS | (cntT << 16);
        __syncthreads();

        // gather: wave 0, lane l owns query l (strict first, then ties, in
        // (chunk, index) order == global index order -> reference tie-break)
        if (w == 0) {
            int outc = 0;
            for (int c2 = 0; c2 < CH; ++c2) {
                int cs = CNTS[c2 * 64 + l] & 0xffff;
                for (int s2 = 0; s2 < cs && outc < KNN; ++s2)
                    IDX[l * KNN + outc++] = JL[(c2 * KNN + s2) * 64 + l];
            }
            for (int c2 = 0; c2 < CH && outc < KNN; ++c2) {
                int ct = CNTS[c2 * 64 + l] >> 16;
                for (int s2 = 0; s2 < ct && outc < KNN; ++s2)
                    IDX[l * KNN + outc++] =
                        JL[(c2 * KNN + (KNN - 1 - s2)) * 64 + l];
            }
        }
        __syncthreads();            // IDX visible; JL/CNTS dead below
    }

    // ======================= Phase B: MFMA edge MLP ========================
    const int c15 = l & 15;
    const int g   = l >> 4;
    const int nbase = b * NPTS + slab * 64;   // block's first node (global)
    const int gbase = b * NPTS;               // batch start row

    float* E = (float*)smem;            // [64][ESTRIDE]
    float* S = (float*)(smem + 16896);  // [64][ESTRIDE]

    const f32x4 zf = {0.f, 0.f, 0.f, 0.f};

    // ---- B1: base/skip for all 64 nodes -> LDS (wave = 16-node grp x 2 f)
    {
        const int ng = w & 3;            // node group 0..3
        const int f0 = (w >> 2) * 2;     // f-slice base: 0 or 2

        const float* rp = x + (size_t)(nbase + ng * 16 + c15) * FIN + g * 8;
        float4 v0 = *(const float4*)rp;
        float4 v1 = *(const float4*)(rp + 4);
        int4 pk = make_int4(bf16pk(v0.x, v0.y), bf16pk(v0.z, v0.w),
                            bf16pk(v1.x, v1.y), bf16pk(v1.z, v1.w));
        bf16x8 afi = *(bf16x8*)&pk;

        #pragma unroll
        for (int ff = 0; ff < 2; ++ff) {
            const int col = 16 * (f0 + ff) + c15;
            unsigned pd[4], pn[4];
            #pragma unroll
            for (int d = 0; d < 4; ++d) {
                const int k0 = g * 8 + 2 * d;
                float h0 = W_edge[(FIN + k0)     * FOUT + col];
                float h1 = W_edge[(FIN + k0 + 1) * FOUT + col];
                pd[d] = bf16pk(W_edge[k0       * FOUT + col] - h0,
                               W_edge[(k0 + 1) * FOUT + col] - h1);
                pn[d] = bf16pk(W_nn[k0 * FOUT + col], W_nn[(k0+1) * FOUT + col]);
            }
            int4 bd = make_int4(pd[0], pd[1], pd[2], pd[3]);
            int4 bn = make_int4(pn[0], pn[1], pn[2], pn[3]);
            f32x4 baseF = __builtin_amdgcn_mfma_f32_16x16x32_bf16(
                afi, *(bf16x8*)&bd, zf, 0, 0, 0);
            f32x4 skipF = __builtin_amdgcn_mfma_f32_16x16x32_bf16(
                afi, *(bf16x8*)&bn, zf, 0, 0, 0);
            const float be  = b_edge[col];
            const float bnn = b_nn[col];
            #pragma unroll
            for (int reg = 0; reg < 4; ++reg) {
                const int nd = ng * 16 + g * 4 + reg;   // node within block
                E[nd * ESTRIDE + col] = baseF[reg] + be;
                S[nd * ESTRIDE + col] = fmaxf(skipF[reg] + bnn, 0.f);
            }
        }
    }
    __syncthreads();   // E/S visible

    // ---- B2: wave = 8 nodes x ALL 4 f-slices (single gather per node) ----
    {
        const int n0l = w * 8;           // first local node of this wave

        int4 Bhi[4];
        #pragma unroll
        for (int ff = 0; ff < 4; ++ff) {
            const int col = 16 * ff + c15;
            unsigned ph[4];
            #pragma unroll
            for (int d = 0; d < 4; ++d) {
                const int k0 = g * 8 + 2 * d;
                ph[d] = bf16pk(W_edge[(FIN + k0)     * FOUT + col],
                               W_edge[(FIN + k0 + 1) * FOUT + col]);
            }
            Bhi[ff] = make_int4(ph[0], ph[1], ph[2], ph[3]);
        }

        int nb0 = IDX[n0l * KNN + c15];
        const float* rpp = x + (size_t)(gbase + nb0) * FIN + g * 8;
        float4 pv0 = *(const float4*)rpp;
        float4 pv1 = *(const float4*)(rpp + 4);

        #pragma unroll 1
        for (int i = 0; i < 8; ++i) {
            float4 c0 = pv0, c1 = pv1;
            if (i < 7) {
                int nb = IDX[(n0l + i + 1) * KNN + c15];
                const float* rp2 = x + (size_t)(gbase + nb) * FIN + g * 8;
                pv0 = *(const float4*)rp2;
                pv1 = *(const float4*)(rp2 + 4);
            }
            int4 pk2 = make_int4(bf16pk(c0.x, c0.y), bf16pk(c0.z, c0.w),
                                 bf16pk(c1.x, c1.y), bf16pk(c1.z, c1.w));
            bf16x8 af = *(bf16x8*)&pk2;

            float rmax[4];
            #pragma unroll
            for (int ff = 0; ff < 4; ++ff) {
                f32x4 z = __builtin_amdgcn_mfma_f32_16x16x32_bf16(
                    af, *(bf16x8*)&Bhi[ff], zf, 0, 0, 0);
                float m = fmaxf(fmaxf(z[0], z[1]), fmaxf(z[2], z[3]));
                m = fmaxf(m, __shfl_xor(m, 16));
                m = fmaxf(m, __shfl_xor(m, 32));
                rmax[ff] = m;
            }
            float val = (g == 0) ? rmax[0] : (g == 1) ? rmax[1]
                      : (g == 2) ? rmax[2] : rmax[3];
            const int nd = n0l + i;
            float e = fmaxf(val + E[nd * ESTRIDE + g * 16 + c15], 0.f);
            float s = S[nd * ESTRIDE + g * 16 + c15];
            out[(size_t)(nbase + nd) * FOUT + g * 16 + c15] = e + s;
        }
    }
}

// ---------------------------------------------------------------------------
extern "C" void kernel_launch(void* const* d_in, const int* in_sizes, int n_in,
                              void* d_out, int out_size, void* d_ws, size_t ws_size,
                              hipStream_t stream) {
    const float* x      = (const float*)d_in[0];
    const float* pos    = (const float*)d_in[1];
    const float* W_edge = (const float*)d_in[2];
    const float* b_edge = (const float*)d_in[3];
    const float* W_nn   = (const float*)d_in[4];
    const float* b_nn   = (const float*)d_in[5];

    float4* P4   = (float4*)d_ws;       // 1 MB
    float*  outp = (float*)d_out;

    sq_kernel     <<<NB * NPTS / 256, 256, 0, stream>>>(pos, P4);
    knn_mlp_kernel<<<NB * 32,         512, 0, stream>>>(P4, x, W_edge, b_edge,
                                                        W_nn, b_nn, outp);
}

// Round 9
// 204.319 us; speedup vs baseline: 1.2201x; 1.0017x over previous
//
#include <hip/hip_runtime.h>

// Problem constants (from reference)
#define NB     32      // B
#define NPTS   2048    // N
#define KNN    16      // K
#define FIN    32      // F_IN
#define FOUT   64      // F_OUT

typedef __attribute__((ext_vector_type(8))) short bf16x8;
typedef __attribute__((ext_vector_type(4))) float f32x4;

// RNE float->bf16 pack
__device__ inline unsigned bf16pk(float lo, float hi) {
    unsigned a = __float_as_uint(lo), b = __float_as_uint(hi);
    a = (a + 0x7fffu + ((a >> 16) & 1u)) >> 16;
    b = (b + 0x7fffu + ((b >> 16) & 1u)) >> 16;
    return (a & 0xffffu) | (b << 16);
}

// ---------------------------------------------------------------------------
// R9 == R8 resubmitted (R8's bench was an infra failure, never evaluated).
// R8: R6 base + provably-safe subset of R7's ideas.
//  - Select pass reads candidates from LDS-staged P (copied from global P4,
//    bit-identical). Extra __syncthreads() between the last select READ and
//    the first V write over the P region -> no mid-phase alias reasoning.
//  - Rescan reads global P4 (verbatim R6 RESC) -> same bits as staged P.
//  - IDX padded to stride 17 (kills 16-way gather-write bank conflicts).
//  - B2 gather: depth-2 prefetch (named buffers, static indexing).
//  - 2 dispatches (sq_kernel unchanged from R6).
//  LDS arena 39168 B: [P/V/JL 32768][CNTS 2048][IDX 4352]; phase B aliases
//  [E 16896][S 16896] over P+CNTS (after a barrier). 4 blocks/CU retained.
// ---------------------------------------------------------------------------

#define CEA(x, y) { float _t = fminf(x, y); y = fmaxf(x, y); x = _t; }
#define CED(x, y) { float _t = fmaxf(x, y); y = fminf(x, y); x = _t; }

#define BMERGE16(dk) \
    CEA(dk[0],dk[8])  CEA(dk[1],dk[9])  CEA(dk[2],dk[10]) CEA(dk[3],dk[11]) \
    CEA(dk[4],dk[12]) CEA(dk[5],dk[13]) CEA(dk[6],dk[14]) CEA(dk[7],dk[15]) \
    CEA(dk[0],dk[4])  CEA(dk[1],dk[5])  CEA(dk[2],dk[6])  CEA(dk[3],dk[7])  \
    CEA(dk[8],dk[12]) CEA(dk[9],dk[13]) CEA(dk[10],dk[14]) CEA(dk[11],dk[15]) \
    CEA(dk[0],dk[2])  CEA(dk[1],dk[3])  CEA(dk[4],dk[6])  CEA(dk[5],dk[7])  \
    CEA(dk[8],dk[10]) CEA(dk[9],dk[11]) CEA(dk[12],dk[14]) CEA(dk[13],dk[15]) \
    CEA(dk[0],dk[1])  CEA(dk[2],dk[3])  CEA(dk[4],dk[5])  CEA(dk[6],dk[7])  \
    CEA(dk[8],dk[9])  CEA(dk[10],dk[11]) CEA(dk[12],dk[13]) CEA(dk[14],dk[15])

#define NET8(a) \
    CED(a[0],a[1]) CED(a[2],a[3]) CED(a[4],a[5]) CED(a[6],a[7]) \
    CED(a[0],a[2]) CED(a[1],a[3]) CED(a[4],a[6]) CED(a[5],a[7]) \
    CED(a[1],a[2]) CED(a[5],a[6]) \
    CED(a[0],a[4]) CED(a[1],a[5]) CED(a[2],a[6]) CED(a[3],a[7]) \
    CED(a[2],a[4]) CED(a[3],a[5]) \
    CED(a[1],a[2]) CED(a[3],a[4]) CED(a[5],a[6])

// ================= K1: (x,y,z,sq) precompute (R6 verbatim) =================
__global__ __launch_bounds__(256) void sq_kernel(
    const float* __restrict__ pos, float4* __restrict__ P4)
{
    const int i = blockIdx.x * 256 + threadIdx.x;   // 0 .. 65535
    const float px = pos[i*3 + 0];
    const float py = pos[i*3 + 1];
    const float pz = pos[i*3 + 2];
    const float sq = __fadd_rn(__fadd_rn(__fmul_rn(px,px), __fmul_rn(py,py)),
                               __fmul_rn(pz,pz));
    P4[i] = make_float4(px, py, pz, sq);
}

// ==================== K2: fused exact 16-NN + edge MLP =====================
#define CH   8
#define CHL  (NPTS / CH)    // 256

// shifted distance: d2' = c.w - 2*dot  (per-query order == true d2 order)
#define D2P(C, DST)                                                        \
    {                                                                      \
        float _dot = __fmaf_rn(me.z, (C).z,                                \
                      __fmaf_rn(me.y, (C).y, __fmul_rn(me.x, (C).x)));     \
        DST = __fmaf_rn(-2.0f, _dot, (C).w);                               \
    }

// 16 candidates from LDS P: two independent sort-8s, merged in order
#define SBATCH2(JB, EXCLF)                                                 \
    {                                                                      \
        float a[8], a2[8];                                                 \
        _Pragma("unroll")                                                  \
        for (int i = 0; i < 8; ++i) {                                      \
            const int j = (JB) + i;                                        \
            const float4 c = P[j];                                         \
            float d2;                                                      \
            D2P(c, d2)                                                     \
            a[i] = (EXCLF && j == q) ? 1e30f : d2;                         \
        }                                                                  \
        _Pragma("unroll")                                                  \
        for (int i = 0; i < 8; ++i) {                                      \
            const int j = (JB) + 8 + i;                                    \
            const float4 c = P[j];                                         \
            float d2;                                                      \
            D2P(c, d2)                                                     \
            a2[i] = (EXCLF && j == q) ? 1e30f : d2;                        \
        }                                                                  \
        NET8(a)                                                            \
        NET8(a2)                                                           \
        _Pragma("unroll")                                                  \
        for (int i = 0; i < 8; ++i) dk[8+i] = fminf(dk[8+i], a[i]);        \
        BMERGE16(dk)                                                       \
        _Pragma("unroll")                                                  \
        for (int i = 0; i < 8; ++i) dk[8+i] = fminf(dk[8+i], a2[i]);       \
        BMERGE16(dk)                                                       \
    }

// rescan append (order within chunk = ascending j -> reference tie-break)
#define APP(DD, JJ)                                                        \
    if ((DD) <= tthr) {                                                    \
        if ((DD) < tthr) {                                                 \
            if (cntS + cntT >= KNN) --cntT;                                \
            JL[base + cntS * 64 + l] = (JJ);                               \
            ++cntS;                                                        \
        } else if (cntS + cntT < KNN) {                                    \
            JL[base + (KNN - 1 - cntT) * 64 + l] = (JJ);                   \
            ++cntT;                                                        \
        }                                                                  \
    }

// rescan: candidates from GLOBAL P4 (same bits as staged LDS P)
#define RESC(JJ, EXCLF)                                                    \
    {                                                                      \
        const float4 c = pb4[(JJ)];                                        \
        float d2;                                                          \
        D2P(c, d2)                                                         \
        if (EXCLF && (JJ) == q) d2 = 1e30f;                                \
        APP(d2, (JJ))                                                      \
    }

#define ESTRIDE 66   // padded row stride for E/S
#define IDXS    17   // padded neighbor-list stride (kills gather conflicts)

__global__ __launch_bounds__(512, 8) void knn_mlp_kernel(
    const float4* __restrict__ P4, const float* __restrict__ x,
    const float* __restrict__ W_edge, const float* __restrict__ b_edge,
    const float* __restrict__ W_nn,   const float* __restrict__ b_nn,
    float* __restrict__ out)
{
    // arena: phase A: [P/V/JL 32768][CNTS 2048][IDX 4352]
    //        phase B: [E 16896][S 16896][... ][IDX 4352]
    __shared__ __attribute__((aligned(16))) char smem[39168];
    float4* P    = (float4*)smem;
    float*  V    = (float*)smem;
    int*    CNTS = (int*)(smem + 32768);
    int*    IDX  = (int*)(smem + 34816);

    const int b    = blockIdx.x >> 5;    // 32 blocks per batch
    const int slab = blockIdx.x & 31;    // 64-query slab within batch
    const int t    = threadIdx.x;
    const int w    = __builtin_amdgcn_readfirstlane(t >> 6);  // chunk id
    const int l    = t & 63;

    const float4* __restrict__ pb4 = P4 + (size_t)b * NPTS;
    const int q = slab * 64 + l;         // query within batch (0..2047)

    // ---- Stage: copy batch (x,y,z,sq) table into LDS (bit-identical) ----
    #pragma unroll
    for (int r = 0; r < 4; ++r) {
        const int j = r * 512 + t;
        P[j] = pb4[j];
    }
    __syncthreads();

    const float4 me = P[q];              // me.w unused (shift dropped)

    // ======================= Phase A: exact 16-NN ==========================
    {
        float dk[KNN];
        #pragma unroll
        for (int s = 0; s < KNN; ++s) dk[s] = 1e30f;

        const int j0  = w * CHL;
        const int exw = slab >> 2;                 // chunk containing q's
        const int lo  = j0 + (slab & 3) * 64;      // 64-range containing q's

        if (w == exw) {
            for (int jb = j0;      jb < lo;        jb += 16) SBATCH2(jb, false)
            for (int jb = lo;      jb < lo + 64;   jb += 16) SBATCH2(jb, true)
            for (int jb = lo + 64; jb < j0 + CHL;  jb += 16) SBATCH2(jb, false)
        } else {
            for (int jb = j0;      jb < j0 + CHL;  jb += 16) SBATCH2(jb, false)
        }

        __syncthreads();   // ALL select reads of P complete before V aliases it

        // per-chunk top-16 -> V (aliases P region; now safe by barrier)
        #pragma unroll
        for (int s = 0; s < KNN; ++s)
            V[(w * KNN + s) * 64 + l] = dk[s];
        __syncthreads();

        for (int c2 = 0; c2 < CH; ++c2) {
            if (c2 == w) continue;
            float v[KNN];
            #pragma unroll
            for (int s2 = 0; s2 < KNN; ++s2)
                v[s2] = V[(c2 * KNN + s2) * 64 + l];
            #pragma unroll
            for (int s = 0; s < KNN; ++s) dk[s] = fminf(dk[s], v[KNN-1-s]);
            BMERGE16(dk)
        }
        const float tthr = dk[KNN-1];
        __syncthreads();            // V dead -> reuse as JL

        // index-recovery rescan from GLOBAL P4 (identical d2' chain)
        int* JL = (int*)V;
        const int base = w * KNN * 64;
        int cntS = 0, cntT = 0;
        if (w == exw) {
            for (int j = j0;      j < lo;        ++j) RESC(j, false)
            for (int j = lo;      j < lo + 64;   ++j) RESC(j, true)
            for (int j = lo + 64; j < j0 + CHL;  ++j) RESC(j, false)
        } else {
            for (int j = j0;      j < j0 + CHL;  ++j) RESC(j, false)
        }
        CNTS[w * 64 + l] = cntS | (cntT << 16);
        __syncthreads();

        // gather: wave 0, lane l owns query l (strict first, then ties, in
        // (chunk, index) order == global index order -> reference tie-break)
        if (w == 0) {
            int outc = 0;
            for (int c2 = 0; c2 < CH; ++c2) {
                int cs = CNTS[c2 * 64 + l] & 0xffff;
                for (int s2 = 0; s2 < cs && outc < KNN; ++s2)
                    IDX[l * IDXS + outc++] = JL[(c2 * KNN + s2) * 64 + l];
            }
            for (int c2 = 0; c2 < CH && outc < KNN; ++c2) {
                int ct = CNTS[c2 * 64 + l] >> 16;
                for (int s2 = 0; s2 < ct && outc < KNN; ++s2)
                    IDX[l * IDXS + outc++] =
                        JL[(c2 * KNN + (KNN - 1 - s2)) * 64 + l];
            }
        }
        __syncthreads();            // IDX visible; JL/CNTS dead below
    }

    // ======================= Phase B: MFMA edge MLP ========================
    const int c15 = l & 15;
    const int g   = l >> 4;
    const int nbase = b * NPTS + slab * 64;   // block's first node (global)
    const int gbase = b * NPTS;               // batch start row

    float* E = (float*)smem;            // [64][ESTRIDE]
    float* S = (float*)(smem + 16896);  // [64][ESTRIDE]

    const f32x4 zf = {0.f, 0.f, 0.f, 0.f};

    // ---- B1: base/skip for all 64 nodes -> LDS (wave = 16-node grp x 2 f)
    {
        const int ng = w & 3;            // node group 0..3
        const int f0 = (w >> 2) * 2;     // f-slice base: 0 or 2

        const float* rp = x + (size_t)(nbase + ng * 16 + c15) * FIN + g * 8;
        float4 v0 = *(const float4*)rp;
        float4 v1 = *(const float4*)(rp + 4);
        int4 pk = make_int4(bf16pk(v0.x, v0.y), bf16pk(v0.z, v0.w),
                            bf16pk(v1.x, v1.y), bf16pk(v1.z, v1.w));
        bf16x8 afi = *(bf16x8*)&pk;

        #pragma unroll
        for (int ff = 0; ff < 2; ++ff) {
            const int col = 16 * (f0 + ff) + c15;
            unsigned pd[4], pn[4];
            #pragma unroll
            for (int d = 0; d < 4; ++d) {
                const int k0 = g * 8 + 2 * d;
                float h0 = W_edge[(FIN + k0)     * FOUT + col];
                float h1 = W_edge[(FIN + k0 + 1) * FOUT + col];
                pd[d] = bf16pk(W_edge[k0       * FOUT + col] - h0,
                               W_edge[(k0 + 1) * FOUT + col] - h1);
                pn[d] = bf16pk(W_nn[k0 * FOUT + col], W_nn[(k0+1) * FOUT + col]);
            }
            int4 bd = make_int4(pd[0], pd[1], pd[2], pd[3]);
            int4 bn = make_int4(pn[0], pn[1], pn[2], pn[3]);
            f32x4 baseF = __builtin_amdgcn_mfma_f32_16x16x32_bf16(
                afi, *(bf16x8*)&bd, zf, 0, 0, 0);
            f32x4 skipF = __builtin_amdgcn_mfma_f32_16x16x32_bf16(
                afi, *(bf16x8*)&bn, zf, 0, 0, 0);
            const float be  = b_edge[col];
            const float bnn = b_nn[col];
            #pragma unroll
            for (int reg = 0; reg < 4; ++reg) {
                const int nd = ng * 16 + g * 4 + reg;   // node within block
                E[nd * ESTRIDE + col] = baseF[reg] + be;
                S[nd * ESTRIDE + col] = fmaxf(skipF[reg] + bnn, 0.f);
            }
        }
    }
    __syncthreads();   // E/S visible

    // ---- B2: wave = 8 nodes x ALL 4 f-slices, depth-2 gather prefetch ----
    {
        const int n0l = w * 8;           // first local node of this wave

        int4 Bhi[4];
        #pragma unroll
        for (int ff = 0; ff < 4; ++ff) {
            const int col = 16 * ff + c15;
            unsigned ph[4];
            #pragma unroll
            for (int d = 0; d < 4; ++d) {
                const int k0 = g * 8 + 2 * d;
                ph[d] = bf16pk(W_edge[(FIN + k0)     * FOUT + col],
                               W_edge[(FIN + k0 + 1) * FOUT + col]);
            }
            Bhi[ff] = make_int4(ph[0], ph[1], ph[2], ph[3]);
        }

        // prime depth-2 pipeline (nodes 0 and 1)
        int nbA = IDX[(n0l + 0) * IDXS + c15];
        int nbB = IDX[(n0l + 1) * IDXS + c15];
        const float* rpA = x + (size_t)(gbase + nbA) * FIN + g * 8;
        const float* rpB = x + (size_t)(gbase + nbB) * FIN + g * 8;
        float4 Aa = *(const float4*)rpA, Ab = *(const float4*)(rpA + 4);
        float4 Ba = *(const float4*)rpB, Bb = *(const float4*)(rpB + 4);

        #pragma unroll 1
        for (int i = 0; i < 8; i += 2) {
            // node i (buffer A), prefetch node i+2 into A
            float4 c0 = Aa, c1 = Ab;
            if (i + 2 < 8) {
                int nb = IDX[(n0l + i + 2) * IDXS + c15];
                const float* rp2 = x + (size_t)(gbase + nb) * FIN + g * 8;
                Aa = *(const float4*)rp2;
                Ab = *(const float4*)(rp2 + 4);
            }
            {
                int4 pk2 = make_int4(bf16pk(c0.x, c0.y), bf16pk(c0.z, c0.w),
                                     bf16pk(c1.x, c1.y), bf16pk(c1.z, c1.w));
                bf16x8 af = *(bf16x8*)&pk2;
                float rmax[4];
                #pragma unroll
                for (int ff = 0; ff < 4; ++ff) {
                    f32x4 z = __builtin_amdgcn_mfma_f32_16x16x32_bf16(
                        af, *(bf16x8*)&Bhi[ff], zf, 0, 0, 0);
                    float m = fmaxf(fmaxf(z[0], z[1]), fmaxf(z[2], z[3]));
                    m = fmaxf(m, __shfl_xor(m, 16));
                    m = fmaxf(m, __shfl_xor(m, 32));
                    rmax[ff] = m;
                }
                float val = (g == 0) ? rmax[0] : (g == 1) ? rmax[1]
                          : (g == 2) ? rmax[2] : rmax[3];
                const int nd = n0l + i;
                float e = fmaxf(val + E[nd * ESTRIDE + g * 16 + c15], 0.f);
                float s = S[nd * ESTRIDE + g * 16 + c15];
                out[(size_t)(nbase + nd) * FOUT + g * 16 + c15] = e + s;
            }

            // node i+1 (buffer B), prefetch node i+3 into B
            float4 d0 = Ba, d1 = Bb;
            if (i + 3 < 8) {
                int nb = IDX[(n0l + i + 3) * IDXS + c15];
                const float* rp2 = x + (size_t)(gbase + nb) * FIN + g * 8;
                Ba = *(const float4*)rp2;
                Bb = *(const float4*)(rp2 + 4);
            }
            {
                int4 pk2 = make_int4(bf16pk(d0.x, d0.y), bf16pk(d0.z, d0.w),
                                     bf16pk(d1.x, d1.y), bf16pk(d1.z, d1.w));
                bf16x8 af = *(bf16x8*)&pk2;
                float rmax[4];
                #pragma unroll
                for (int ff = 0; ff < 4; ++ff) {
                    f32x4 z = __builtin_amdgcn_mfma_f32_16x16x32_bf16(
                        af, *(bf16x8*)&Bhi[ff], zf, 0, 0, 0);
                    float m = fmaxf(fmaxf(z[0], z[1]), fmaxf(z[2], z[3]));
                    m = fmaxf(m, __shfl_xor(m, 16));
                    m = fmaxf(m, __shfl_xor(m, 32));
                    rmax[ff] = m;
                }
                float val = (g == 0) ? rmax[0] : (g == 1) ? rmax[1]
                          : (g == 2) ? rmax[2] : rmax[3];
                const int nd = n0l + i + 1;
                float e = fmaxf(val + E[nd * ESTRIDE + g * 16 + c15], 0.f);
                float s = S[nd * ESTRIDE + g * 16 + c15];
                out[(size_t)(nbase + nd) * FOUT + g * 16 + c15] = e + s;
            }
        }
    }
}

// ---------------------------------------------------------------------------
extern "C" void kernel_launch(void* const* d_in, const int* in_sizes, int n_in,
                              void* d_out, int out_size, void* d_ws, size_t ws_size,
                              hipStream_t stream) {
    const float* x      = (const float*)d_in[0];
    const float* pos    = (const float*)d_in[1];
    const float* W_edge = (const float*)d_in[2];
    const float* b_edge = (const float*)d_in[3];
    const float* W_nn   = (const float*)d_in[4];
    const float* b_nn   = (const float*)d_in[5];

    float4* P4   = (float4*)d_ws;       // 1 MB
    float*  outp = (float*)d_out;

    sq_kernel     <<<NB * NPTS / 256, 256, 0, stream>>>(pos, P4);
    knn_mlp_kernel<<<NB * 32,         512, 0, stream>>>(P4, x, W_edge, b_edge,
                                                        W_nn, b_nn, outp);
}

// Round 11
// 196.187 us; speedup vs baseline: 1.2707x; 1.0415x over previous
//
#include <hip/hip_runtime.h>

// Problem constants (from reference)
#define NB     32      // B
#define NPTS   2048    // N
#define KNN    16      // K
#define FIN    32      // F_IN
#define FOUT   64      // F_OUT

typedef __attribute__((ext_vector_type(8))) short bf16x8;
typedef __attribute__((ext_vector_type(4))) float f32x4;

// RNE float->bf16 pack
__device__ inline unsigned bf16pk(float lo, float hi) {
    unsigned a = __float_as_uint(lo), b = __float_as_uint(hi);
    a = (a + 0x7fffu + ((a >> 16) & 1u)) >> 16;
    b = (b + 0x7fffu + ((b >> 16) & 1u)) >> 16;
    return (a & 0xffffu) | (b << 16);
}

// ---------------------------------------------------------------------------
// R11: best verified parts only.
//  - Phase A == R6 verbatim (global P4 select via scalar-cache s_loads,
//    global P4 rescan -> same physical values, no chain-recompute).
//    [R7/R10 post-mortem: rescan-recompute-from-pos crashes 2/2 — a 1-bit
//    chain divergence overruns cntS -> LDS OOB -> garbage IDX -> wild
//    gather -> GPU fault. Retired permanently.]
//  - Phase B == R9 verbatim (IDX stride-17 padding, depth-2 B2 prefetch).
//  - NEW: XCD-aware block swizzle — all 32 blocks of a batch on one XCD:
//    b = ((orig&7)<<2)|((orig>>3)&3), slab = orig>>5  (bijective on 1024).
//    Per-XCD L2 working set: ~8MB -> ~1MB => B2 gather becomes L2-resident.
//  LDS arena 39168 B: [V/JL 32768][CNTS 2048][IDX 4352]; phase B aliases
//  [E 16896][S 16896] over V+CNTS (barrier-separated). 4 blocks/CU.
// ---------------------------------------------------------------------------

#define CEA(x, y) { float _t = fminf(x, y); y = fmaxf(x, y); x = _t; }
#define CED(x, y) { float _t = fmaxf(x, y); y = fminf(x, y); x = _t; }

#define BMERGE16(dk) \
    CEA(dk[0],dk[8])  CEA(dk[1],dk[9])  CEA(dk[2],dk[10]) CEA(dk[3],dk[11]) \
    CEA(dk[4],dk[12]) CEA(dk[5],dk[13]) CEA(dk[6],dk[14]) CEA(dk[7],dk[15]) \
    CEA(dk[0],dk[4])  CEA(dk[1],dk[5])  CEA(dk[2],dk[6])  CEA(dk[3],dk[7])  \
    CEA(dk[8],dk[12]) CEA(dk[9],dk[13]) CEA(dk[10],dk[14]) CEA(dk[11],dk[15]) \
    CEA(dk[0],dk[2])  CEA(dk[1],dk[3])  CEA(dk[4],dk[6])  CEA(dk[5],dk[7])  \
    CEA(dk[8],dk[10]) CEA(dk[9],dk[11]) CEA(dk[12],dk[14]) CEA(dk[13],dk[15]) \
    CEA(dk[0],dk[1])  CEA(dk[2],dk[3])  CEA(dk[4],dk[5])  CEA(dk[6],dk[7])  \
    CEA(dk[8],dk[9])  CEA(dk[10],dk[11]) CEA(dk[12],dk[13]) CEA(dk[14],dk[15])

#define NET8(a) \
    CED(a[0],a[1]) CED(a[2],a[3]) CED(a[4],a[5]) CED(a[6],a[7]) \
    CED(a[0],a[2]) CED(a[1],a[3]) CED(a[4],a[6]) CED(a[5],a[7]) \
    CED(a[1],a[2]) CED(a[5],a[6]) \
    CED(a[0],a[4]) CED(a[1],a[5]) CED(a[2],a[6]) CED(a[3],a[7]) \
    CED(a[2],a[4]) CED(a[3],a[5]) \
    CED(a[1],a[2]) CED(a[3],a[4]) CED(a[5],a[6])

// ================= K1: (x,y,z,sq) precompute (R6 verbatim) =================
__global__ __launch_bounds__(256) void sq_kernel(
    const float* __restrict__ pos, float4* __restrict__ P4)
{
    const int i = blockIdx.x * 256 + threadIdx.x;   // 0 .. 65535
    const float px = pos[i*3 + 0];
    const float py = pos[i*3 + 1];
    const float pz = pos[i*3 + 2];
    const float sq = __fadd_rn(__fadd_rn(__fmul_rn(px,px), __fmul_rn(py,py)),
                               __fmul_rn(pz,pz));
    P4[i] = make_float4(px, py, pz, sq);
}

// ==================== K2: fused exact 16-NN + edge MLP =====================
#define CH   8
#define CHL  (NPTS / CH)    // 256

// shifted distance: d2' = c.w - 2*dot  (per-query order == true d2 order)
#define D2P(C, DST)                                                        \
    {                                                                      \
        float _dot = __fmaf_rn(me.z, (C).z,                                \
                      __fmaf_rn(me.y, (C).y, __fmul_rn(me.x, (C).x)));     \
        DST = __fmaf_rn(-2.0f, _dot, (C).w);                               \
    }

// 16 candidates from global P4: two independent sort-8s, merged in order
#define SBATCH2(JB, EXCLF)                                                 \
    {                                                                      \
        float a[8], a2[8];                                                 \
        _Pragma("unroll")                                                  \
        for (int i = 0; i < 8; ++i) {                                      \
            const int j = (JB) + i;                                        \
            const float4 c = pb4[j];                                       \
            float d2;                                                      \
            D2P(c, d2)                                                     \
            a[i] = (EXCLF && j == q) ? 1e30f : d2;                         \
        }                                                                  \
        _Pragma("unroll")                                                  \
        for (int i = 0; i < 8; ++i) {                                      \
            const int j = (JB) + 8 + i;                                    \
            const float4 c = pb4[j];                                       \
            float d2;                                                      \
            D2P(c, d2)                                                     \
            a2[i] = (EXCLF && j == q) ? 1e30f : d2;                        \
        }                                                                  \
        NET8(a)                                                            \
        NET8(a2)                                                           \
        _Pragma("unroll")                                                  \
        for (int i = 0; i < 8; ++i) dk[8+i] = fminf(dk[8+i], a[i]);        \
        BMERGE16(dk)                                                       \
        _Pragma("unroll")                                                  \
        for (int i = 0; i < 8; ++i) dk[8+i] = fminf(dk[8+i], a2[i]);       \
        BMERGE16(dk)                                                       \
    }

// rescan append (order within chunk = ascending j -> reference tie-break)
#define APP(DD, JJ)                                                        \
    if ((DD) <= tthr) {                                                    \
        if ((DD) < tthr) {                                                 \
            if (cntS + cntT >= KNN) --cntT;                                \
            JL[base + cntS * 64 + l] = (JJ);                               \
            ++cntS;                                                        \
        } else if (cntS + cntT < KNN) {                                    \
            JL[base + (KNN - 1 - cntT) * 64 + l] = (JJ);                   \
            ++cntT;                                                        \
        }                                                                  \
    }

// rescan: candidates from GLOBAL P4 (same physical values as select pass)
#define RESC(JJ, EXCLF)                                                    \
    {                                                                      \
        const float4 c = pb4[(JJ)];                                        \
        float d2;                                                          \
        D2P(c, d2)                                                         \
        if (EXCLF && (JJ) == q) d2 = 1e30f;                                \
        APP(d2, (JJ))                                                      \
    }

#define ESTRIDE 66   // padded row stride for E/S
#define IDXS    17   // padded neighbor-list stride (kills gather conflicts)

__global__ __launch_bounds__(512, 8) void knn_mlp_kernel(
    const float4* __restrict__ P4, const float* __restrict__ x,
    const float* __restrict__ W_edge, const float* __restrict__ b_edge,
    const float* __restrict__ W_nn,   const float* __restrict__ b_nn,
    float* __restrict__ out)
{
    // arena: phase A: [V/JL 32768][CNTS 2048][IDX 4352]
    //        phase B: [E 16896][S 16896][... ][IDX 4352]
    __shared__ __attribute__((aligned(16))) char smem[39168];
    float* V    = (float*)smem;
    int*   CNTS = (int*)(smem + 32768);
    int*   IDX  = (int*)(smem + 34816);

    // XCD-aware swizzle: batch b's 32 blocks all share orig%8 == b>>2,
    // i.e. one XCD (dispatch round-robins blockIdx across the 8 XCDs).
    const int orig = blockIdx.x;
    const int b    = ((orig & 7) << 2) | ((orig >> 3) & 3);  // batch 0..31
    const int slab = orig >> 5;                              // slab  0..31
    const int t    = threadIdx.x;
    const int w    = __builtin_amdgcn_readfirstlane(t >> 6);  // chunk id
    const int l    = t & 63;

    const float4* __restrict__ pb4 = P4 + (size_t)b * NPTS;
    const int    q  = slab * 64 + l;     // query within batch (0..2047)
    const float4 me = pb4[q];            // me.w unused (shift dropped)

    // ======================= Phase A: exact 16-NN ==========================
    {
        float dk[KNN];
        #pragma unroll
        for (int s = 0; s < KNN; ++s) dk[s] = 1e30f;

        const int j0  = w * CHL;
        const int exw = slab >> 2;                 // chunk containing q's
        const int lo  = j0 + (slab & 3) * 64;      // 64-range containing q's

        if (w == exw) {
            for (int jb = j0;      jb < lo;        jb += 16) SBATCH2(jb, false)
            for (int jb = lo;      jb < lo + 64;   jb += 16) SBATCH2(jb, true)
            for (int jb = lo + 64; jb < j0 + CHL;  jb += 16) SBATCH2(jb, false)
        } else {
            for (int jb = j0;      jb < j0 + CHL;  jb += 16) SBATCH2(jb, false)
        }

        // cross-chunk merge of the 8 per-chunk top-16 lists
        #pragma unroll
        for (int s = 0; s < KNN; ++s)
            V[(w * KNN + s) * 64 + l] = dk[s];
        __syncthreads();

        for (int c2 = 0; c2 < CH; ++c2) {
            if (c2 == w) continue;
            float v[KNN];
            #pragma unroll
            for (int s2 = 0; s2 < KNN; ++s2)
                v[s2] = V[(c2 * KNN + s2) * 64 + l];
            #pragma unroll
            for (int s = 0; s < KNN; ++s) dk[s] = fminf(dk[s], v[KNN-1-s]);
            BMERGE16(dk)
        }
        const float tthr = dk[KNN-1];
        __syncthreads();            // V dead -> reuse as JL

        // index-recovery rescan from GLOBAL P4 (identical d2' chain)
        int* JL = (int*)V;
        const int base = w * KNN * 64;
        int cntS = 0, cntT = 0;
        if (w == exw) {
            for (int j = j0;      j < lo;        ++j) RESC(j, false)
            for (int j = lo;      j < lo + 64;   ++j) RESC(j, true)
            for (int j = lo + 64; j < j0 + CHL;  ++j) RESC(j, false)
        } else {
            for (int j = j0;      j < j0 + CHL;  ++j) RESC(j, false)
        }
        CNTS[w * 64 + l] = cntS | (cntT << 16);
        __syncthreads();

        // gather: wave 0, lane l owns query l (strict first, then ties, in
        // (chunk, index) order == global index order -> reference tie-break)
        if (w == 0) {
            int outc = 0;
            for (int c2 = 0; c2 < CH; ++c2) {
                int cs = CNTS[c2 * 64 + l] & 0xffff;
                for (int s2 = 0; s2 < cs && outc < KNN; ++s2)
                    IDX[l * IDXS + outc++] = JL[(c2 * KNN + s2) * 64 + l];
            }
            for (int c2 = 0; c2 < CH && outc < KNN; ++c2) {
                int ct = CNTS[c2 * 64 + l] >> 16;
                for (int s2 = 0; s2 < ct && outc < KNN; ++s2)
                    IDX[l * IDXS + outc++] =
                        JL[(c2 * KNN + (KNN - 1 - s2)) * 64 + l];
            }
        }
        __syncthreads();            // IDX visible; JL/CNTS dead below
    }

    // ======================= Phase B: MFMA edge MLP ========================
    const int c15 = l & 15;
    const int g   = l >> 4;
    const int nbase = b * NPTS + slab * 64;   // block's first node (global)
    const int gbase = b * NPTS;               // batch start row

    float* E = (float*)smem;            // [64][ESTRIDE]
    float* S = (float*)(smem + 16896);  // [64][ESTRIDE]

    const f32x4 zf = {0.f, 0.f, 0.f, 0.f};

    // ---- B1: base/skip for all 64 nodes -> LDS (wave = 16-node grp x 2 f)
    {
        const int ng = w & 3;            // node group 0..3
        const int f0 = (w >> 2) * 2;     // f-slice base: 0 or 2

        const float* rp = x + (size_t)(nbase + ng * 16 + c15) * FIN + g * 8;
        float4 v0 = *(const float4*)rp;
        float4 v1 = *(const float4*)(rp + 4);
        int4 pk = make_int4(bf16pk(v0.x, v0.y), bf16pk(v0.z, v0.w),
                            bf16pk(v1.x, v1.y), bf16pk(v1.z, v1.w));
        bf16x8 afi = *(bf16x8*)&pk;

        #pragma unroll
        for (int ff = 0; ff < 2; ++ff) {
            const int col = 16 * (f0 + ff) + c15;
            unsigned pd[4], pn[4];
            #pragma unroll
            for (int d = 0; d < 4; ++d) {
                const int k0 = g * 8 + 2 * d;
                float h0 = W_edge[(FIN + k0)     * FOUT + col];
                float h1 = W_edge[(FIN + k0 + 1) * FOUT + col];
                pd[d] = bf16pk(W_edge[k0       * FOUT + col] - h0,
                               W_edge[(k0 + 1) * FOUT + col] - h1);
                pn[d] = bf16pk(W_nn[k0 * FOUT + col], W_nn[(k0+1) * FOUT + col]);
            }
            int4 bd = make_int4(pd[0], pd[1], pd[2], pd[3]);
            int4 bn = make_int4(pn[0], pn[1], pn[2], pn[3]);
            f32x4 baseF = __builtin_amdgcn_mfma_f32_16x16x32_bf16(
                afi, *(bf16x8*)&bd, zf, 0, 0, 0);
            f32x4 skipF = __builtin_amdgcn_mfma_f32_16x16x32_bf16(
                afi, *(bf16x8*)&bn, zf, 0, 0, 0);
            const float be  = b_edge[col];
            const float bnn = b_nn[col];
            #pragma unroll
            for (int reg = 0; reg < 4; ++reg) {
                const int nd = ng * 16 + g * 4 + reg;   // node within block
                E[nd * ESTRIDE + col] = baseF[reg] + be;
                S[nd * ESTRIDE + col] = fmaxf(skipF[reg] + bnn, 0.f);
            }
        }
    }
    __syncthreads();   // E/S visible

    // ---- B2: wave = 8 nodes x ALL 4 f-slices, depth-2 gather prefetch ----
    {
        const int n0l = w * 8;           // first local node of this wave

        int4 Bhi[4];
        #pragma unroll
        for (int ff = 0; ff < 4; ++ff) {
            const int col = 16 * ff + c15;
            unsigned ph[4];
            #pragma unroll
            for (int d = 0; d < 4; ++d) {
                const int k0 = g * 8 + 2 * d;
                ph[d] = bf16pk(W_edge[(FIN + k0)     * FOUT + col],
                               W_edge[(FIN + k0 + 1) * FOUT + col]);
            }
            Bhi[ff] = make_int4(ph[0], ph[1], ph[2], ph[3]);
        }

        // prime depth-2 pipeline (nodes 0 and 1)
        int nbA = IDX[(n0l + 0) * IDXS + c15];
        int nbB = IDX[(n0l + 1) * IDXS + c15];
        const float* rpA = x + (size_t)(gbase + nbA) * FIN + g * 8;
        const float* rpB = x + (size_t)(gbase + nbB) * FIN + g * 8;
        float4 Aa = *(const float4*)rpA, Ab = *(const float4*)(rpA + 4);
        float4 Ba = *(const float4*)rpB, Bb = *(const float4*)(rpB + 4);

        #pragma unroll 1
        for (int i = 0; i < 8; i += 2) {
            // node i (buffer A), prefetch node i+2 into A
            float4 c0 = Aa, c1 = Ab;
            if (i + 2 < 8) {
                int nb = IDX[(n0l + i + 2) * IDXS + c15];
                const float* rp2 = x + (size_t)(gbase + nb) * FIN + g * 8;
                Aa = *(const float4*)rp2;
                Ab = *(const float4*)(rp2 + 4);
            }
            {
                int4 pk2 = make_int4(bf16pk(c0.x, c0.y), bf16pk(c0.z, c0.w),
                                     bf16pk(c1.x, c1.y), bf16pk(c1.z, c1.w));
                bf16x8 af = *(bf16x8*)&pk2;
                float rmax[4];
                #pragma unroll
                for (int ff = 0; ff < 4; ++ff) {
                    f32x4 z = __builtin_amdgcn_mfma_f32_16x16x32_bf16(
                        af, *(bf16x8*)&Bhi[ff], zf, 0, 0, 0);
                    float m = fmaxf(fmaxf(z[0], z[1]), fmaxf(z[2], z[3]));
                    m = fmaxf(m, __shfl_xor(m, 16));
                    m = fmaxf(m, __shfl_xor(m, 32));
                    rmax[ff] = m;
                }
                float val = (g == 0) ? rmax[0] : (g == 1) ? rmax[1]
                          : (g == 2) ? rmax[2] : rmax[3];
                const int nd = n0l + i;
                float e = fmaxf(val + E[nd * ESTRIDE + g * 16 + c15], 0.f);
                float s = S[nd * ESTRIDE + g * 16 + c15];
                out[(size_t)(nbase + nd) * FOUT + g * 16 + c15] = e + s;
            }

            // node i+1 (buffer B), prefetch node i+3 into B
            float4 d0 = Ba, d1 = Bb;
            if (i + 3 < 8) {
                int nb = IDX[(n0l + i + 3) * IDXS + c15];
                const float* rp2 = x + (size_t)(gbase + nb) * FIN + g * 8;
                Ba = *(const float4*)rp2;
                Bb = *(const float4*)(rp2 + 4);
            }
            {
                int4 pk2 = make_int4(bf16pk(d0.x, d0.y), bf16pk(d0.z, d0.w),
                                     bf16pk(d1.x, d1.y), bf16pk(d1.z, d1.w));
                bf16x8 af = *(bf16x8*)&pk2;
                float rmax[4];
                #pragma unroll
                for (int ff = 0; ff < 4; ++ff) {
                    f32x4 z = __builtin_amdgcn_mfma_f32_16x16x32_bf16(
                        af, *(bf16x8*)&Bhi[ff], zf, 0, 0, 0);
                    float m = fmaxf(fmaxf(z[0], z[1]), fmaxf(z[2], z[3]));
                    m = fmaxf(m, __shfl_xor(m, 16));
                    m = fmaxf(m, __shfl_xor(m, 32));
                    rmax[ff] = m;
                }
                float val = (g == 0) ? rmax[0] : (g == 1) ? rmax[1]
                          : (g == 2) ? rmax[2] : rmax[3];
                const int nd = n0l + i + 1;
                float e = fmaxf(val + E[nd * ESTRIDE + g * 16 + c15], 0.f);
                float s = S[nd * ESTRIDE + g * 16 + c15];
                out[(size_t)(nbase + nd) * FOUT + g * 16 + c15] = e + s;
            }
        }
    }
}

// ---------------------------------------------------------------------------
extern "C" void kernel_launch(void* const* d_in, const int* in_sizes, int n_in,
                              void* d_out, int out_size, void* d_ws, size_t ws_size,
                              hipStream_t stream) {
    const float* x      = (const float*)d_in[0];
    const float* pos    = (const float*)d_in[1];
    const float* W_edge = (const float*)d_in[2];
    const float* b_edge = (const float*)d_in[3];
    const float* W_nn   = (const float*)d_in[4];
    const float* b_nn   = (const float*)d_in[5];

    float4* P4   = (float4*)d_ws;       // 1 MB
    float*  outp = (float*)d_out;

    sq_kernel     <<<NB * NPTS / 256, 256, 0, stream>>>(pos, P4);
    knn_mlp_kernel<<<NB * 32,         512, 0, stream>>>(P4, x, W_edge, b_edge,
                                                        W_nn, b_nn, outp);
}

// Round 13
// 187.536 us; speedup vs baseline: 1.3293x; 1.0461x over previous
//
#include <hip/hip_runtime.h>

// Problem constants (from reference)
#define NB     32      // B
#define NPTS   2048    // N
#define KNN    16      // K
#define FIN    32      // F_IN
#define FOUT   64      // F_OUT

typedef __attribute__((ext_vector_type(8))) short bf16x8;
typedef __attribute__((ext_vector_type(4))) float f32x4;

// RNE float->bf16 pack
__device__ inline unsigned bf16pk(float lo, float hi) {
    unsigned a = __float_as_uint(lo), b = __float_as_uint(hi);
    a = (a + 0x7fffu + ((a >> 16) & 1u)) >> 16;
    b = (b + 0x7fffu + ((b >> 16) & 1u)) >> 16;
    return (a & 0xffffu) | (b << 16);
}

// ---------------------------------------------------------------------------
// R13 == R12 resubmitted (R12's bench was a container/infra failure — same
// signature as R8, which passed unchanged on resubmission as R9).
// R12: R11 + batched rescan (the only change; bit-exact).
//  Remaining stall density is the rescan: 1-candidate-per-iteration loop
//  with runtime trip counts -> serial s_load latency chain (256 iters/wave).
//  Fix: RESCB16 — hoist 16 candidate loads + D2P into unrolled register
//  arrays, then run the 16 APP checks in the ORIGINAL ascending order.
//  Same chain, same compare order, same tie machinery -> bit-identical kNN.
//  All range boundaries are multiples of 64 -> stride 16 always divides.
// ---------------------------------------------------------------------------

#define CEA(x, y) { float _t = fminf(x, y); y = fmaxf(x, y); x = _t; }
#define CED(x, y) { float _t = fmaxf(x, y); y = fminf(x, y); x = _t; }

#define BMERGE16(dk) \
    CEA(dk[0],dk[8])  CEA(dk[1],dk[9])  CEA(dk[2],dk[10]) CEA(dk[3],dk[11]) \
    CEA(dk[4],dk[12]) CEA(dk[5],dk[13]) CEA(dk[6],dk[14]) CEA(dk[7],dk[15]) \
    CEA(dk[0],dk[4])  CEA(dk[1],dk[5])  CEA(dk[2],dk[6])  CEA(dk[3],dk[7])  \
    CEA(dk[8],dk[12]) CEA(dk[9],dk[13]) CEA(dk[10],dk[14]) CEA(dk[11],dk[15]) \
    CEA(dk[0],dk[2])  CEA(dk[1],dk[3])  CEA(dk[4],dk[6])  CEA(dk[5],dk[7])  \
    CEA(dk[8],dk[10]) CEA(dk[9],dk[11]) CEA(dk[12],dk[14]) CEA(dk[13],dk[15]) \
    CEA(dk[0],dk[1])  CEA(dk[2],dk[3])  CEA(dk[4],dk[5])  CEA(dk[6],dk[7])  \
    CEA(dk[8],dk[9])  CEA(dk[10],dk[11]) CEA(dk[12],dk[13]) CEA(dk[14],dk[15])

#define NET8(a) \
    CED(a[0],a[1]) CED(a[2],a[3]) CED(a[4],a[5]) CED(a[6],a[7]) \
    CED(a[0],a[2]) CED(a[1],a[3]) CED(a[4],a[6]) CED(a[5],a[7]) \
    CED(a[1],a[2]) CED(a[5],a[6]) \
    CED(a[0],a[4]) CED(a[1],a[5]) CED(a[2],a[6]) CED(a[3],a[7]) \
    CED(a[2],a[4]) CED(a[3],a[5]) \
    CED(a[1],a[2]) CED(a[3],a[4]) CED(a[5],a[6])

// ================= K1: (x,y,z,sq) precompute (verbatim) ====================
__global__ __launch_bounds__(256) void sq_kernel(
    const float* __restrict__ pos, float4* __restrict__ P4)
{
    const int i = blockIdx.x * 256 + threadIdx.x;   // 0 .. 65535
    const float px = pos[i*3 + 0];
    const float py = pos[i*3 + 1];
    const float pz = pos[i*3 + 2];
    const float sq = __fadd_rn(__fadd_rn(__fmul_rn(px,px), __fmul_rn(py,py)),
                               __fmul_rn(pz,pz));
    P4[i] = make_float4(px, py, pz, sq);
}

// ==================== K2: fused exact 16-NN + edge MLP =====================
#define CH   8
#define CHL  (NPTS / CH)    // 256

// shifted distance: d2' = c.w - 2*dot  (per-query order == true d2 order)
#define D2P(C, DST)                                                        \
    {                                                                      \
        float _dot = __fmaf_rn(me.z, (C).z,                                \
                      __fmaf_rn(me.y, (C).y, __fmul_rn(me.x, (C).x)));     \
        DST = __fmaf_rn(-2.0f, _dot, (C).w);                               \
    }

// 16 candidates from global P4: two independent sort-8s, merged in order
#define SBATCH2(JB, EXCLF)                                                 \
    {                                                                      \
        float a[8], a2[8];                                                 \
        _Pragma("unroll")                                                  \
        for (int i = 0; i < 8; ++i) {                                      \
            const int j = (JB) + i;                                        \
            const float4 c = pb4[j];                                       \
            float d2;                                                      \
            D2P(c, d2)                                                     \
            a[i] = (EXCLF && j == q) ? 1e30f : d2;                         \
        }                                                                  \
        _Pragma("unroll")                                                  \
        for (int i = 0; i < 8; ++i) {                                      \
            const int j = (JB) + 8 + i;                                    \
            const float4 c = pb4[j];                                       \
            float d2;                                                      \
            D2P(c, d2)                                                     \
            a2[i] = (EXCLF && j == q) ? 1e30f : d2;                        \
        }                                                                  \
        NET8(a)                                                            \
        NET8(a2)                                                           \
        _Pragma("unroll")                                                  \
        for (int i = 0; i < 8; ++i) dk[8+i] = fminf(dk[8+i], a[i]);        \
        BMERGE16(dk)                                                       \
        _Pragma("unroll")                                                  \
        for (int i = 0; i < 8; ++i) dk[8+i] = fminf(dk[8+i], a2[i]);       \
        BMERGE16(dk)                                                       \
    }

// rescan append (order within chunk = ascending j -> reference tie-break)
#define APP(DD, JJ)                                                        \
    if ((DD) <= tthr) {                                                    \
        if ((DD) < tthr) {                                                 \
            if (cntS + cntT >= KNN) --cntT;                                \
            JL[base + cntS * 64 + l] = (JJ);                               \
            ++cntS;                                                        \
        } else if (cntS + cntT < KNN) {                                    \
            JL[base + (KNN - 1 - cntT) * 64 + l] = (JJ);                   \
            ++cntT;                                                        \
        }                                                                  \
    }

// batched rescan: 16 loads+D2P hoisted into registers, then the 16 APP
// checks in the ORIGINAL ascending order (bit-identical to 1-at-a-time)
#define RESCB16(JB, EXCLF)                                                 \
    {                                                                      \
        float dd[16];                                                      \
        _Pragma("unroll")                                                  \
        for (int i = 0; i < 16; ++i) {                                     \
            const float4 c = pb4[(JB) + i];                                \
            float d2;                                                      \
            D2P(c, d2)                                                     \
            dd[i] = (EXCLF && ((JB) + i) == q) ? 1e30f : d2;               \
        }                                                                  \
        _Pragma("unroll")                                                  \
        for (int i = 0; i < 16; ++i) { APP(dd[i], (JB) + i) }              \
    }

#define ESTRIDE 66   // padded row stride for E/S
#define IDXS    17   // padded neighbor-list stride (kills gather conflicts)

__global__ __launch_bounds__(512, 8) void knn_mlp_kernel(
    const float4* __restrict__ P4, const float* __restrict__ x,
    const float* __restrict__ W_edge, const float* __restrict__ b_edge,
    const float* __restrict__ W_nn,   const float* __restrict__ b_nn,
    float* __restrict__ out)
{
    // arena: phase A: [V/JL 32768][CNTS 2048][IDX 4352]
    //        phase B: [E 16896][S 16896][... ][IDX 4352]
    __shared__ __attribute__((aligned(16))) char smem[39168];
    float* V    = (float*)smem;
    int*   CNTS = (int*)(smem + 32768);
    int*   IDX  = (int*)(smem + 34816);

    // XCD-aware swizzle: batch b's 32 blocks all share orig%8 == b>>2,
    // i.e. one XCD (dispatch round-robins blockIdx across the 8 XCDs).
    const int orig = blockIdx.x;
    const int b    = ((orig & 7) << 2) | ((orig >> 3) & 3);  // batch 0..31
    const int slab = orig >> 5;                              // slab  0..31
    const int t    = threadIdx.x;
    const int w    = __builtin_amdgcn_readfirstlane(t >> 6);  // chunk id
    const int l    = t & 63;

    const float4* __restrict__ pb4 = P4 + (size_t)b * NPTS;
    const int    q  = slab * 64 + l;     // query within batch (0..2047)
    const float4 me = pb4[q];            // me.w unused (shift dropped)

    // ======================= Phase A: exact 16-NN ==========================
    {
        float dk[KNN];
        #pragma unroll
        for (int s = 0; s < KNN; ++s) dk[s] = 1e30f;

        const int j0  = w * CHL;
        const int exw = slab >> 2;                 // chunk containing q's
        const int lo  = j0 + (slab & 3) * 64;      // 64-range containing q's

        if (w == exw) {
            for (int jb = j0;      jb < lo;        jb += 16) SBATCH2(jb, false)
            for (int jb = lo;      jb < lo + 64;   jb += 16) SBATCH2(jb, true)
            for (int jb = lo + 64; jb < j0 + CHL;  jb += 16) SBATCH2(jb, false)
        } else {
            for (int jb = j0;      jb < j0 + CHL;  jb += 16) SBATCH2(jb, false)
        }

        // cross-chunk merge of the 8 per-chunk top-16 lists
        #pragma unroll
        for (int s = 0; s < KNN; ++s)
            V[(w * KNN + s) * 64 + l] = dk[s];
        __syncthreads();

        for (int c2 = 0; c2 < CH; ++c2) {
            if (c2 == w) continue;
            float v[KNN];
            #pragma unroll
            for (int s2 = 0; s2 < KNN; ++s2)
                v[s2] = V[(c2 * KNN + s2) * 64 + l];
            #pragma unroll
            for (int s = 0; s < KNN; ++s) dk[s] = fminf(dk[s], v[KNN-1-s]);
            BMERGE16(dk)
        }
        const float tthr = dk[KNN-1];
        __syncthreads();            // V dead -> reuse as JL

        // index-recovery rescan from GLOBAL P4 (identical d2' chain),
        // batched 16-wide: loads hoisted, append order preserved
        int* JL = (int*)V;
        const int base = w * KNN * 64;
        int cntS = 0, cntT = 0;
        if (w == exw) {
            for (int j = j0;      j < lo;        j += 16) RESCB16(j, false)
            for (int j = lo;      j < lo + 64;   j += 16) RESCB16(j, true)
            for (int j = lo + 64; j < j0 + CHL;  j += 16) RESCB16(j, false)
        } else {
            for (int j = j0;      j < j0 + CHL;  j += 16) RESCB16(j, false)
        }
        CNTS[w * 64 + l] = cntS | (cntT << 16);
        __syncthreads();

        // gather: wave 0, lane l owns query l (strict first, then ties, in
        // (chunk, index) order == global index order -> reference tie-break)
        if (w == 0) {
            int outc = 0;
            for (int c2 = 0; c2 < CH; ++c2) {
                int cs = CNTS[c2 * 64 + l] & 0xffff;
                for (int s2 = 0; s2 < cs && outc < KNN; ++s2)
                    IDX[l * IDXS + outc++] = JL[(c2 * KNN + s2) * 64 + l];
            }
            for (int c2 = 0; c2 < CH && outc < KNN; ++c2) {
                int ct = CNTS[c2 * 64 + l] >> 16;
                for (int s2 = 0; s2 < ct && outc < KNN; ++s2)
                    IDX[l * IDXS + outc++] =
                        JL[(c2 * KNN + (KNN - 1 - s2)) * 64 + l];
            }
        }
        __syncthreads();            // IDX visible; JL/CNTS dead below
    }

    // ======================= Phase B: MFMA edge MLP ========================
    const int c15 = l & 15;
    const int g   = l >> 4;
    const int nbase = b * NPTS + slab * 64;   // block's first node (global)
    const int gbase = b * NPTS;               // batch start row

    float* E = (float*)smem;            // [64][ESTRIDE]
    float* S = (float*)(smem + 16896);  // [64][ESTRIDE]

    const f32x4 zf = {0.f, 0.f, 0.f, 0.f};

    // ---- B1: base/skip for all 64 nodes -> LDS (wave = 16-node grp x 2 f)
    {
        const int ng = w & 3;            // node group 0..3
        const int f0 = (w >> 2) * 2;     // f-slice base: 0 or 2

        const float* rp = x + (size_t)(nbase + ng * 16 + c15) * FIN + g * 8;
        float4 v0 = *(const float4*)rp;
        float4 v1 = *(const float4*)(rp + 4);
        int4 pk = make_int4(bf16pk(v0.x, v0.y), bf16pk(v0.z, v0.w),
                            bf16pk(v1.x, v1.y), bf16pk(v1.z, v1.w));
        bf16x8 afi = *(bf16x8*)&pk;

        #pragma unroll
        for (int ff = 0; ff < 2; ++ff) {
            const int col = 16 * (f0 + ff) + c15;
            unsigned pd[4], pn[4];
            #pragma unroll
            for (int d = 0; d < 4; ++d) {
                const int k0 = g * 8 + 2 * d;
                float h0 = W_edge[(FIN + k0)     * FOUT + col];
                float h1 = W_edge[(FIN + k0 + 1) * FOUT + col];
                pd[d] = bf16pk(W_edge[k0       * FOUT + col] - h0,
                               W_edge[(k0 + 1) * FOUT + col] - h1);
                pn[d] = bf16pk(W_nn[k0 * FOUT + col], W_nn[(k0+1) * FOUT + col]);
            }
            int4 bd = make_int4(pd[0], pd[1], pd[2], pd[3]);
            int4 bn = make_int4(pn[0], pn[1], pn[2], pn[3]);
            f32x4 baseF = __builtin_amdgcn_mfma_f32_16x16x32_bf16(
                afi, *(bf16x8*)&bd, zf, 0, 0, 0);
            f32x4 skipF = __builtin_amdgcn_mfma_f32_16x16x32_bf16(
                afi, *(bf16x8*)&bn, zf, 0, 0, 0);
            const float be  = b_edge[col];
            const float bnn = b_nn[col];
            #pragma unroll
            for (int reg = 0; reg < 4; ++reg) {
                const int nd = ng * 16 + g * 4 + reg;   // node within block
                E[nd * ESTRIDE + col] = baseF[reg] + be;
                S[nd * ESTRIDE + col] = fmaxf(skipF[reg] + bnn, 0.f);
            }
        }
    }
    __syncthreads();   // E/S visible

    // ---- B2: wave = 8 nodes x ALL 4 f-slices, depth-2 gather prefetch ----
    {
        const int n0l = w * 8;           // first local node of this wave

        int4 Bhi[4];
        #pragma unroll
        for (int ff = 0; ff < 4; ++ff) {
            const int col = 16 * ff + c15;
            unsigned ph[4];
            #pragma unroll
            for (int d = 0; d < 4; ++d) {
                const int k0 = g * 8 + 2 * d;
                ph[d] = bf16pk(W_edge[(FIN + k0)     * FOUT + col],
                               W_edge[(FIN + k0 + 1) * FOUT + col]);
            }
            Bhi[ff] = make_int4(ph[0], ph[1], ph[2], ph[3]);
        }

        // prime depth-2 pipeline (nodes 0 and 1)
        int nbA = IDX[(n0l + 0) * IDXS + c15];
        int nbB = IDX[(n0l + 1) * IDXS + c15];
        const float* rpA = x + (size_t)(gbase + nbA) * FIN + g * 8;
        const float* rpB = x + (size_t)(gbase + nbB) * FIN + g * 8;
        float4 Aa = *(const float4*)rpA, Ab = *(const float4*)(rpA + 4);
        float4 Ba = *(const float4*)rpB, Bb = *(const float4*)(rpB + 4);

        #pragma unroll 1
        for (int i = 0; i < 8; i += 2) {
            // node i (buffer A), prefetch node i+2 into A
            float4 c0 = Aa, c1 = Ab;
            if (i + 2 < 8) {
                int nb = IDX[(n0l + i + 2) * IDXS + c15];
                const float* rp2 = x + (size_t)(gbase + nb) * FIN + g * 8;
                Aa = *(const float4*)rp2;
                Ab = *(const float4*)(rp2 + 4);
            }
            {
                int4 pk2 = make_int4(bf16pk(c0.x, c0.y), bf16pk(c0.z, c0.w),
                                     bf16pk(c1.x, c1.y), bf16pk(c1.z, c1.w));
                bf16x8 af = *(bf16x8*)&pk2;
                float rmax[4];
                #pragma unroll
                for (int ff = 0; ff < 4; ++ff) {
                    f32x4 z = __builtin_amdgcn_mfma_f32_16x16x32_bf16(
                        af, *(bf16x8*)&Bhi[ff], zf, 0, 0, 0);
                    float m = fmaxf(fmaxf(z[0], z[1]), fmaxf(z[2], z[3]));
                    m = fmaxf(m, __shfl_xor(m, 16));
                    m = fmaxf(m, __shfl_xor(m, 32));
                    rmax[ff] = m;
                }
                float val = (g == 0) ? rmax[0] : (g == 1) ? rmax[1]
                          : (g == 2) ? rmax[2] : rmax[3];
                const int nd = n0l + i;
                float e = fmaxf(val + E[nd * ESTRIDE + g * 16 + c15], 0.f);
                float s = S[nd * ESTRIDE + g * 16 + c15];
                out[(size_t)(nbase + nd) * FOUT + g * 16 + c15] = e + s;
            }

            // node i+1 (buffer B), prefetch node i+3 into B
            float4 d0 = Ba, d1 = Bb;
            if (i + 3 < 8) {
                int nb = IDX[(n0l + i + 3) * IDXS + c15];
                const float* rp2 = x + (size_t)(gbase + nb) * FIN + g * 8;
                Ba = *(const float4*)rp2;
                Bb = *(const float4*)(rp2 + 4);
            }
            {
                int4 pk2 = make_int4(bf16pk(d0.x, d0.y), bf16pk(d0.z, d0.w),
                                     bf16pk(d1.x, d1.y), bf16pk(d1.z, d1.w));
                bf16x8 af = *(bf16x8*)&pk2;
                float rmax[4];
                #pragma unroll
                for (int ff = 0; ff < 4; ++ff) {
                    f32x4 z = __builtin_amdgcn_mfma_f32_16x16x32_bf16(
                        af, *(bf16x8*)&Bhi[ff], zf, 0, 0, 0);
                    float m = fmaxf(fmaxf(z[0], z[1]), fmaxf(z[2], z[3]));
                    m = fmaxf(m, __shfl_xor(m, 16));
                    m = fmaxf(m, __shfl_xor(m, 32));
                    rmax[ff] = m;
                }
                float val = (g == 0) ? rmax[0] : (g == 1) ? rmax[1]
                          : (g == 2) ? rmax[2] : rmax[3];
                const int nd = n0l + i + 1;
                float e = fmaxf(val + E[nd * ESTRIDE + g * 16 + c15], 0.f);
                float s = S[nd * ESTRIDE + g * 16 + c15];
                out[(size_t)(nbase + nd) * FOUT + g * 16 + c15] = e + s;
            }
        }
    }
}

// ---------------------------------------------------------------------------
extern "C" void kernel_launch(void* const* d_in, const int* in_sizes, int n_in,
                              void* d_out, int out_size, void* d_ws, size_t ws_size,
                              hipStream_t stream) {
    const float* x      = (const float*)d_in[0];
    const float* pos    = (const float*)d_in[1];
    const float* W_edge = (const float*)d_in[2];
    const float* b_edge = (const float*)d_in[3];
    const float* W_nn   = (const float*)d_in[4];
    const float* b_nn   = (const float*)d_in[5];

    float4* P4   = (float4*)d_ws;       // 1 MB
    float*  outp = (float*)d_out;

    sq_kernel     <<<NB * NPTS / 256, 256, 0, stream>>>(pos, P4);
    knn_mlp_kernel<<<NB * 32,         512, 0, stream>>>(P4, x, W_edge, b_edge,
                                                        W_nn, b_nn, outp);
}